// Round 2
// baseline (1678.354 us; speedup 1.0000x reference)
//
#include <hip/hip_runtime.h>
#include <hip/hip_bf16.h>

#define N_NODES 25000
#define N_EDGES 600000
#define ACT_NONE 0
#define ACT_RELU 1
#define ACT_LEAKY 2

// ---------------------------------------------------------------------------
// CSR construction
// ---------------------------------------------------------------------------
__global__ __launch_bounds__(256) void hist_kernel(const int* __restrict__ dst,
                                                   int* __restrict__ deg, int E) {
    int e = blockIdx.x * 256 + threadIdx.x;
    if (e < E) atomicAdd(&deg[dst[e]], 1);
}

__global__ __launch_bounds__(1024) void scan_kernel(const int* __restrict__ deg,
                                                    int* __restrict__ off,
                                                    int* __restrict__ cursor, int n) {
    __shared__ int s[1024];
    int t = threadIdx.x;
    int carry = 0;
    for (int base = 0; base < n; base += 1024) {
        int v = (base + t < n) ? deg[base + t] : 0;
        s[t] = v;
        __syncthreads();
        #pragma unroll
        for (int d = 1; d < 1024; d <<= 1) {
            int x = (t >= d) ? s[t - d] : 0;
            __syncthreads();
            s[t] += x;
            __syncthreads();
        }
        int excl = s[t] - v;
        if (base + t < n) {
            off[base + t] = carry + excl;
            cursor[base + t] = carry + excl;
        }
        int total = s[1023];
        __syncthreads();
        carry += total;
    }
    if (t == 0) off[n] = carry;
}

__global__ __launch_bounds__(256) void scatter_kernel(const int* __restrict__ src,
                                                      const int* __restrict__ dst,
                                                      int* __restrict__ cursor,
                                                      int* __restrict__ csr_src, int E) {
    int e = blockIdx.x * 256 + threadIdx.x;
    if (e < E) {
        int d = dst[e];
        int pos = atomicAdd(&cursor[d], 1);
        csr_src[pos] = src[e];
    }
}

// ---------------------------------------------------------------------------
// SAGE mean aggregation: mean[i][c] = (1/max(deg,1)) * sum_{e in in(i)} h[src[e]][c]
// one block (256 threads = 256 feature channels) per node
// ---------------------------------------------------------------------------
__global__ __launch_bounds__(256) void sage_mean_kernel(const float* __restrict__ h,
                                                        const int* __restrict__ off,
                                                        const int* __restrict__ csr_src,
                                                        float* __restrict__ mean) {
    int i = blockIdx.x;
    int c = threadIdx.x;
    int s0 = off[i], s1 = off[i + 1];
    float acc = 0.0f;
    for (int e = s0; e < s1; ++e) {
        int s = csr_src[e];
        acc += h[(long)s * 256 + c];
    }
    float inv = 1.0f / fmaxf((float)(s1 - s0), 1.0f);
    mean[(long)i * 256 + c] = acc * inv;
}

// ---------------------------------------------------------------------------
// Tiled fp32 dual-GEMM: C[M,O] = act(A1[M,K]·W1[O,K]^T (+ A2·W2^T) + bias)
// BM=BO=64, BK=32, 256 threads, 4x4 outputs/thread
// ---------------------------------------------------------------------------
__global__ __launch_bounds__(256) void gemm_dual_kernel(
    const float* __restrict__ A1, const float* __restrict__ W1,
    const float* __restrict__ A2, const float* __restrict__ W2,
    const float* __restrict__ bias, float* __restrict__ C,
    int M, int K, int O, int act)
{
    __shared__ float As[32][65];
    __shared__ float Ws[32][65];
    int tid = threadIdx.x;
    int row0 = blockIdx.x * 64;
    int col0 = blockIdx.y * 64;
    int tm = (tid >> 4) * 4;
    int to = (tid & 15) * 4;
    float acc[4][4] = {};

    for (int pass = 0; pass < 2; ++pass) {
        const float* A = pass ? A2 : A1;
        const float* W = pass ? W2 : W1;
        if (A == nullptr) continue;
        for (int k0 = 0; k0 < K; k0 += 32) {
            #pragma unroll
            for (int i = 0; i < 8; ++i) {
                int idx = tid + i * 256;
                int m  = idx >> 5;
                int kk = idx & 31;
                int gr = row0 + m;
                As[kk][m] = (gr < M) ? A[(long)gr * K + k0 + kk] : 0.0f;
                Ws[kk][m] = W[(long)(col0 + m) * K + k0 + kk];
            }
            __syncthreads();
            #pragma unroll
            for (int kk = 0; kk < 32; ++kk) {
                float a0 = As[kk][tm], a1 = As[kk][tm + 1], a2 = As[kk][tm + 2], a3 = As[kk][tm + 3];
                float w0 = Ws[kk][to], w1 = Ws[kk][to + 1], w2 = Ws[kk][to + 2], w3 = Ws[kk][to + 3];
                acc[0][0] += a0 * w0; acc[0][1] += a0 * w1; acc[0][2] += a0 * w2; acc[0][3] += a0 * w3;
                acc[1][0] += a1 * w0; acc[1][1] += a1 * w1; acc[1][2] += a1 * w2; acc[1][3] += a1 * w3;
                acc[2][0] += a2 * w0; acc[2][1] += a2 * w1; acc[2][2] += a2 * w2; acc[2][3] += a2 * w3;
                acc[3][0] += a3 * w0; acc[3][1] += a3 * w1; acc[3][2] += a3 * w2; acc[3][3] += a3 * w3;
            }
            __syncthreads();
        }
    }

    #pragma unroll
    for (int i = 0; i < 4; ++i) {
        int gr = row0 + tm + i;
        if (gr >= M) continue;
        #pragma unroll
        for (int j = 0; j < 4; ++j) {
            int gc = col0 + to + j;
            float v = acc[i][j] + bias[gc];
            if (act == ACT_RELU)       v = fmaxf(v, 0.0f);
            else if (act == ACT_LEAKY) v = (v > 0.0f) ? v : 0.01f * v;
            C[(long)gr * O + gc] = v;
        }
    }
}

// ---------------------------------------------------------------------------
// Per-edge MLP: val = relu(dot96)·edge_attr + relu(dot32)
// ---------------------------------------------------------------------------
__global__ __launch_bounds__(256) void edge_kernel(const float* __restrict__ h,
                                                   const int* __restrict__ src,
                                                   const int* __restrict__ dst,
                                                   const float* __restrict__ eattr,
                                                   const float* __restrict__ w96,
                                                   const float* __restrict__ b96,
                                                   const float* __restrict__ w32,
                                                   const float* __restrict__ b32,
                                                   float* __restrict__ vals, int E) {
    __shared__ float sw96[192];
    __shared__ float sw32[64];
    int t = threadIdx.x;
    if (t < 192) sw96[t] = w96[t];
    if (t < 64)  sw32[t] = w32[t];
    __syncthreads();
    int e = blockIdx.x * 256 + t;
    if (e >= E) return;
    const float* xl = h + (long)src[e] * 128;
    const float* xr = h + (long)dst[e] * 128;
    float a96 = 0.0f, a32 = 0.0f;
    #pragma unroll
    for (int c = 0; c < 96; c += 4) {
        float4 l = *(const float4*)(xl + c);
        float4 r = *(const float4*)(xr + c);
        a96 += l.x * sw96[c] + l.y * sw96[c + 1] + l.z * sw96[c + 2] + l.w * sw96[c + 3];
        a96 += r.x * sw96[96 + c] + r.y * sw96[97 + c] + r.z * sw96[98 + c] + r.w * sw96[99 + c];
    }
    #pragma unroll
    for (int c = 0; c < 32; c += 4) {
        float4 l = *(const float4*)(xl + 96 + c);
        float4 r = *(const float4*)(xr + 96 + c);
        a32 += l.x * sw32[c] + l.y * sw32[c + 1] + l.z * sw32[c + 2] + l.w * sw32[c + 3];
        a32 += r.x * sw32[32 + c] + r.y * sw32[33 + c] + r.z * sw32[34 + c] + r.w * sw32[35 + c];
    }
    float f96 = fmaxf(a96 + b96[0], 0.0f);
    float f32v = fmaxf(a32 + b32[0], 0.0f);
    vals[e] = f96 * eattr[e] + f32v;
}

__global__ __launch_bounds__(256) void group_mean_kernel(const float* __restrict__ vals,
                                                         float* __restrict__ out, int G) {
    int g = blockIdx.x * 256 + threadIdx.x;
    if (g >= G) return;
    float s = 0.0f;
    #pragma unroll
    for (int k = 0; k < 48; ++k) s += vals[g * 48 + k];
    out[g] = s * (1.0f / 48.0f);
}

// ---------------------------------------------------------------------------
extern "C" void kernel_launch(void* const* d_in, const int* in_sizes, int n_in,
                              void* d_out, int out_size, void* d_ws, size_t ws_size,
                              hipStream_t stream) {
    const float* x         = (const float*)d_in[0];
    const int*   edge_idx  = (const int*)d_in[1];
    const float* edge_attr = (const float*)d_in[2];
    const float* prelin_w  = (const float*)d_in[4];
    const float* prelin_b  = (const float*)d_in[5];
    const float* conv1_lw  = (const float*)d_in[6];
    const float* conv1_lb  = (const float*)d_in[7];
    const float* conv1_rw  = (const float*)d_in[8];
    const float* conv2_lw  = (const float*)d_in[9];
    const float* conv2_lb  = (const float*)d_in[10];
    const float* conv2_rw  = (const float*)d_in[11];
    const float* conv3_lw  = (const float*)d_in[12];
    const float* conv3_lb  = (const float*)d_in[13];
    const float* conv3_rw  = (const float*)d_in[14];
    const float* hh1_w     = (const float*)d_in[15];
    const float* hh1_b     = (const float*)d_in[16];
    const float* hh2_w     = (const float*)d_in[17];
    const float* hh2_b     = (const float*)d_in[18];
    const float* oo_w      = (const float*)d_in[19];
    const float* oo_b      = (const float*)d_in[20];
    const float* lin96_w   = (const float*)d_in[21];
    const float* lin96_b   = (const float*)d_in[22];
    const float* lin32_w   = (const float*)d_in[23];
    const float* lin32_b   = (const float*)d_in[24];

    const int* src = edge_idx;
    const int* dst = edge_idx + N_EDGES;

    // workspace layout
    float* bufA  = (float*)d_ws;                 // N x 256
    float* bufB  = bufA + (long)N_NODES * 256;   // N x 256
    float* bufC  = bufB + (long)N_NODES * 256;   // N x 256
    float* evals = bufC + (long)N_NODES * 256;   // E
    int* deg     = (int*)(evals + N_EDGES);      // N
    int* off     = deg + N_NODES;                // N+1
    int* cursor  = off + N_NODES + 1;            // N
    int* csr_src = cursor + N_NODES;             // E

    const int EB = (N_EDGES + 255) / 256;
    const int MB = (N_NODES + 63) / 64;   // 391

    // CSR build
    (void)hipMemsetAsync(deg, 0, N_NODES * sizeof(int), stream);
    hist_kernel<<<EB, 256, 0, stream>>>(dst, deg, N_EDGES);
    scan_kernel<<<1, 1024, 0, stream>>>(deg, off, cursor, N_NODES);
    scatter_kernel<<<EB, 256, 0, stream>>>(src, dst, cursor, csr_src, N_EDGES);

    // prelin: h = relu(x @ prelin_w^T + b)  [N,256]
    gemm_dual_kernel<<<dim3(MB, 4), 256, 0, stream>>>(
        x, prelin_w, nullptr, nullptr, prelin_b, bufA, N_NODES, 128, 256, ACT_RELU);

    // conv1 + hh1
    sage_mean_kernel<<<N_NODES, 256, 0, stream>>>(bufA, off, csr_src, bufB);
    gemm_dual_kernel<<<dim3(MB, 4), 256, 0, stream>>>(
        bufB, conv1_lw, bufA, conv1_rw, conv1_lb, bufC, N_NODES, 256, 256, ACT_RELU);
    gemm_dual_kernel<<<dim3(MB, 4), 256, 0, stream>>>(
        bufC, hh1_w, nullptr, nullptr, hh1_b, bufA, N_NODES, 256, 256, ACT_LEAKY);

    // conv2 + hh2
    sage_mean_kernel<<<N_NODES, 256, 0, stream>>>(bufA, off, csr_src, bufB);
    gemm_dual_kernel<<<dim3(MB, 4), 256, 0, stream>>>(
        bufB, conv2_lw, bufA, conv2_rw, conv2_lb, bufC, N_NODES, 256, 256, ACT_RELU);
    gemm_dual_kernel<<<dim3(MB, 4), 256, 0, stream>>>(
        bufC, hh2_w, nullptr, nullptr, hh2_b, bufA, N_NODES, 256, 256, ACT_LEAKY);

    // conv3 (O=128) + oo
    sage_mean_kernel<<<N_NODES, 256, 0, stream>>>(bufA, off, csr_src, bufB);
    gemm_dual_kernel<<<dim3(MB, 2), 256, 0, stream>>>(
        bufB, conv3_lw, bufA, conv3_rw, conv3_lb, bufC, N_NODES, 256, 128, ACT_RELU);
    gemm_dual_kernel<<<dim3(MB, 2), 256, 0, stream>>>(
        bufC, oo_w, nullptr, nullptr, oo_b, bufA, N_NODES, 128, 128, ACT_LEAKY);

    // edge MLP + 48-group mean
    edge_kernel<<<EB, 256, 0, stream>>>(bufA, src, dst, edge_attr,
                                        lin96_w, lin96_b, lin32_w, lin32_b,
                                        evals, N_EDGES);
    const int G = N_EDGES / 48;
    group_mean_kernel<<<(G + 255) / 256, 256, 0, stream>>>(evals, (float*)d_out, G);
}

// Round 3
// 867.808 us; speedup vs baseline: 1.9340x; 1.9340x over previous
//
#include <hip/hip_runtime.h>
#include <hip/hip_bf16.h>

#define N_NODES 25000
#define N_EDGES 600000
#define ACT_NONE 0
#define ACT_RELU 1
#define ACT_LEAKY 2

typedef __bf16 bf16x8 __attribute__((ext_vector_type(8)));
typedef float f32x4 __attribute__((ext_vector_type(4)));
typedef unsigned short u16x8 __attribute__((ext_vector_type(8)));

__device__ __forceinline__ unsigned short f2bf(float x) {
    union { float f; unsigned int u; } v; v.f = x;
    unsigned int r = (v.u + 0x7fffu + ((v.u >> 16) & 1u)) >> 16;
    return (unsigned short)r;
}
__device__ __forceinline__ float bf2f(unsigned short b) {
    union { float f; unsigned int u; } v; v.u = ((unsigned int)b) << 16;
    return v.f;
}

// ---------------------------------------------------------------------------
// CSR construction
// ---------------------------------------------------------------------------
__global__ __launch_bounds__(256) void hist_kernel(const int* __restrict__ dst,
                                                   int* __restrict__ deg, int E) {
    int e = blockIdx.x * 256 + threadIdx.x;
    if (e < E) atomicAdd(&deg[dst[e]], 1);
}

__global__ __launch_bounds__(1024) void scan_kernel(const int* __restrict__ deg,
                                                    int* __restrict__ off,
                                                    int* __restrict__ cursor, int n) {
    __shared__ int s[1024];
    int t = threadIdx.x;
    int carry = 0;
    for (int base = 0; base < n; base += 1024) {
        int v = (base + t < n) ? deg[base + t] : 0;
        s[t] = v;
        __syncthreads();
        #pragma unroll
        for (int d = 1; d < 1024; d <<= 1) {
            int x = (t >= d) ? s[t - d] : 0;
            __syncthreads();
            s[t] += x;
            __syncthreads();
        }
        int excl = s[t] - v;
        if (base + t < n) {
            off[base + t] = carry + excl;
            cursor[base + t] = carry + excl;
        }
        int total = s[1023];
        __syncthreads();
        carry += total;
    }
    if (t == 0) off[n] = carry;
}

__global__ __launch_bounds__(256) void scatter_kernel(const int* __restrict__ src,
                                                      const int* __restrict__ dst,
                                                      int* __restrict__ cursor,
                                                      int* __restrict__ csr_src, int E) {
    int e = blockIdx.x * 256 + threadIdx.x;
    if (e < E) {
        int d = dst[e];
        int pos = atomicAdd(&cursor[d], 1);
        csr_src[pos] = src[e];
    }
}

// ---------------------------------------------------------------------------
// fp32 -> bf16 hi/lo pair conversion
// ---------------------------------------------------------------------------
__global__ __launch_bounds__(256) void convert_kernel(const float* __restrict__ src,
                                                      unsigned short* __restrict__ hi,
                                                      unsigned short* __restrict__ lo, int n) {
    int i = blockIdx.x * 256 + threadIdx.x;
    if (i < n) {
        float x = src[i];
        unsigned short h = f2bf(x);
        hi[i] = h;
        lo[i] = f2bf(x - bf2f(h));
    }
}

// ---------------------------------------------------------------------------
// SAGE mean aggregation -> bf16 hi/lo pair output
// ---------------------------------------------------------------------------
__global__ __launch_bounds__(256) void sage_mean_kernel(const float* __restrict__ h,
                                                        const int* __restrict__ off,
                                                        const int* __restrict__ csr_src,
                                                        unsigned short* __restrict__ mh,
                                                        unsigned short* __restrict__ ml) {
    int i = blockIdx.x;
    int c = threadIdx.x;
    int s0 = off[i], s1 = off[i + 1];
    float acc = 0.0f;
    for (int e = s0; e < s1; ++e) {
        int s = csr_src[e];
        acc += h[(long)s * 256 + c];
    }
    float inv = 1.0f / fmaxf((float)(s1 - s0), 1.0f);
    float m = acc * inv;
    unsigned short hb = f2bf(m);
    mh[(long)i * 256 + c] = hb;
    ml[(long)i * 256 + c] = f2bf(m - bf2f(hb));
}

// ---------------------------------------------------------------------------
// MFMA split-bf16 dual GEMM: C[M,O] = act(A1·W1^T (+ A2·W2^T) + bias)
// A,W given as bf16 hi/lo pairs. acc += hi*hi + hi*lo + lo*hi (3-pass).
// Tile 128x128, BK=32, 256 threads (4 waves, 2x2 of 64x64).
// ---------------------------------------------------------------------------
__global__ __launch_bounds__(256, 2) void gemm_mfma_kernel(
    const unsigned short* __restrict__ A1h, const unsigned short* __restrict__ A1l,
    const unsigned short* __restrict__ W1h, const unsigned short* __restrict__ W1l,
    const unsigned short* __restrict__ A2h, const unsigned short* __restrict__ A2l,
    const unsigned short* __restrict__ W2h, const unsigned short* __restrict__ W2l,
    const float* __restrict__ bias,
    float* __restrict__ Cf, unsigned short* __restrict__ Ch, unsigned short* __restrict__ Cl,
    int M, int K, int O, int act)
{
    __shared__ unsigned short sAh[128][40];
    __shared__ unsigned short sAl[128][40];
    __shared__ unsigned short sWh[128][40];
    __shared__ unsigned short sWl[128][40];

    int tid = threadIdx.x;
    int row0 = blockIdx.x * 128;
    int col0 = blockIdx.y * 128;
    int wid = tid >> 6, lane = tid & 63;
    int wm = (wid >> 1) * 64, wo = (wid & 1) * 64;
    int fr = lane & 15, kb = (lane >> 4) * 8;

    f32x4 acc[4][4] = {};

    for (int pass = 0; pass < 2; ++pass) {
        const unsigned short* Ah = pass ? A2h : A1h;
        const unsigned short* Al = pass ? A2l : A1l;
        const unsigned short* Wh = pass ? W2h : W1h;
        const unsigned short* Wl = pass ? W2l : W1l;
        if (Ah == nullptr) continue;
        for (int k0 = 0; k0 < K; k0 += 32) {
            #pragma unroll
            for (int i = 0; i < 2; ++i) {
                int chunk = tid + i * 256;      // 0..511
                int r = chunk >> 2;             // 0..127
                int cq = (chunk & 3) * 8;       // 0,8,16,24
                int ga = row0 + r;
                u16x8 zero = (u16x8)0;
                u16x8 va_h = (ga < M) ? *(const u16x8*)&Ah[(long)ga * K + k0 + cq] : zero;
                u16x8 va_l = (ga < M) ? *(const u16x8*)&Al[(long)ga * K + k0 + cq] : zero;
                u16x8 vw_h = *(const u16x8*)&Wh[(long)(col0 + r) * K + k0 + cq];
                u16x8 vw_l = *(const u16x8*)&Wl[(long)(col0 + r) * K + k0 + cq];
                *(u16x8*)&sAh[r][cq] = va_h;
                *(u16x8*)&sAl[r][cq] = va_l;
                *(u16x8*)&sWh[r][cq] = vw_h;
                *(u16x8*)&sWl[r][cq] = vw_l;
            }
            __syncthreads();
            bf16x8 ah[4], al[4], bh[4], bl[4];
            #pragma unroll
            for (int i = 0; i < 4; ++i) {
                ah[i] = *(const bf16x8*)&sAh[wm + i * 16 + fr][kb];
                al[i] = *(const bf16x8*)&sAl[wm + i * 16 + fr][kb];
                bh[i] = *(const bf16x8*)&sWh[wo + i * 16 + fr][kb];
                bl[i] = *(const bf16x8*)&sWl[wo + i * 16 + fr][kb];
            }
            #pragma unroll
            for (int i = 0; i < 4; ++i) {
                #pragma unroll
                for (int j = 0; j < 4; ++j) {
                    acc[i][j] = __builtin_amdgcn_mfma_f32_16x16x32_bf16(ah[i], bh[j], acc[i][j], 0, 0, 0);
                    acc[i][j] = __builtin_amdgcn_mfma_f32_16x16x32_bf16(ah[i], bl[j], acc[i][j], 0, 0, 0);
                    acc[i][j] = __builtin_amdgcn_mfma_f32_16x16x32_bf16(al[i], bh[j], acc[i][j], 0, 0, 0);
                }
            }
            __syncthreads();
        }
    }

    // epilogue: C/D layout col=lane&15, row=(lane>>4)*4+reg  [m89-verified]
    int rgrp = (lane >> 4) * 4;
    int cl_ = lane & 15;
    #pragma unroll
    for (int i = 0; i < 4; ++i) {
        #pragma unroll
        for (int j = 0; j < 4; ++j) {
            int gcol = col0 + wo + j * 16 + cl_;
            float bv = bias[gcol];
            #pragma unroll
            for (int r = 0; r < 4; ++r) {
                int grow = row0 + wm + i * 16 + rgrp + r;
                if (grow < M) {
                    float v = acc[i][j][r] + bv;
                    if (act == ACT_RELU)       v = fmaxf(v, 0.0f);
                    else if (act == ACT_LEAKY) v = (v > 0.0f) ? v : 0.01f * v;
                    long idx = (long)grow * O + gcol;
                    if (Cf) Cf[idx] = v;
                    if (Ch) {
                        unsigned short hbits = f2bf(v);
                        Ch[idx] = hbits;
                        Cl[idx] = f2bf(v - bf2f(hbits));
                    }
                }
            }
        }
    }
}

// ---------------------------------------------------------------------------
// Per-edge MLP: val = relu(dot96)*edge_attr + relu(dot32)
// ---------------------------------------------------------------------------
__global__ __launch_bounds__(256) void edge_kernel(const float* __restrict__ h,
                                                   const int* __restrict__ src,
                                                   const int* __restrict__ dst,
                                                   const float* __restrict__ eattr,
                                                   const float* __restrict__ w96,
                                                   const float* __restrict__ b96,
                                                   const float* __restrict__ w32,
                                                   const float* __restrict__ b32,
                                                   float* __restrict__ vals, int E) {
    __shared__ float sw96[192];
    __shared__ float sw32[64];
    int t = threadIdx.x;
    if (t < 192) sw96[t] = w96[t];
    if (t < 64)  sw32[t] = w32[t];
    __syncthreads();
    int e = blockIdx.x * 256 + t;
    if (e >= E) return;
    const float* xl = h + (long)src[e] * 128;
    const float* xr = h + (long)dst[e] * 128;
    float a96 = 0.0f, a32 = 0.0f;
    #pragma unroll
    for (int c = 0; c < 96; c += 4) {
        float4 l = *(const float4*)(xl + c);
        float4 r = *(const float4*)(xr + c);
        a96 += l.x * sw96[c] + l.y * sw96[c + 1] + l.z * sw96[c + 2] + l.w * sw96[c + 3];
        a96 += r.x * sw96[96 + c] + r.y * sw96[97 + c] + r.z * sw96[98 + c] + r.w * sw96[99 + c];
    }
    #pragma unroll
    for (int c = 0; c < 32; c += 4) {
        float4 l = *(const float4*)(xl + 96 + c);
        float4 r = *(const float4*)(xr + 96 + c);
        a32 += l.x * sw32[c] + l.y * sw32[c + 1] + l.z * sw32[c + 2] + l.w * sw32[c + 3];
        a32 += r.x * sw32[32 + c] + r.y * sw32[33 + c] + r.z * sw32[34 + c] + r.w * sw32[35 + c];
    }
    float f96 = fmaxf(a96 + b96[0], 0.0f);
    float f32v = fmaxf(a32 + b32[0], 0.0f);
    vals[e] = f96 * eattr[e] + f32v;
}

__global__ __launch_bounds__(256) void group_mean_kernel(const float* __restrict__ vals,
                                                         float* __restrict__ out, int G) {
    int g = blockIdx.x * 256 + threadIdx.x;
    if (g >= G) return;
    float s = 0.0f;
    #pragma unroll
    for (int k = 0; k < 48; ++k) s += vals[g * 48 + k];
    out[g] = s * (1.0f / 48.0f);
}

// ---------------------------------------------------------------------------
extern "C" void kernel_launch(void* const* d_in, const int* in_sizes, int n_in,
                              void* d_out, int out_size, void* d_ws, size_t ws_size,
                              hipStream_t stream) {
    const float* x         = (const float*)d_in[0];
    const int*   edge_idx  = (const int*)d_in[1];
    const float* edge_attr = (const float*)d_in[2];
    const float* prelin_w  = (const float*)d_in[4];
    const float* prelin_b  = (const float*)d_in[5];
    const float* conv1_lw  = (const float*)d_in[6];
    const float* conv1_lb  = (const float*)d_in[7];
    const float* conv1_rw  = (const float*)d_in[8];
    const float* conv2_lw  = (const float*)d_in[9];
    const float* conv2_lb  = (const float*)d_in[10];
    const float* conv2_rw  = (const float*)d_in[11];
    const float* conv3_lw  = (const float*)d_in[12];
    const float* conv3_lb  = (const float*)d_in[13];
    const float* conv3_rw  = (const float*)d_in[14];
    const float* hh1_w     = (const float*)d_in[15];
    const float* hh1_b     = (const float*)d_in[16];
    const float* hh2_w     = (const float*)d_in[17];
    const float* hh2_b     = (const float*)d_in[18];
    const float* oo_w      = (const float*)d_in[19];
    const float* oo_b      = (const float*)d_in[20];
    const float* lin96_w   = (const float*)d_in[21];
    const float* lin96_b   = (const float*)d_in[22];
    const float* lin32_w   = (const float*)d_in[23];
    const float* lin32_b   = (const float*)d_in[24];

    const int* src = edge_idx;
    const int* dst = edge_idx + N_EDGES;

    // ---- workspace carve-up ----
    char* wsp = (char*)d_ws;
    size_t used = 0;
    auto alloc = [&](size_t bytes) -> char* {
        char* r = wsp;
        size_t pad = (bytes + 255) & ~(size_t)255;
        wsp += pad; used += pad;
        return r;
    };
    float* bufF = (float*)alloc((size_t)N_NODES * 256 * 4);
    unsigned short* P0h = (unsigned short*)alloc((size_t)N_NODES * 256 * 2);
    unsigned short* P0l = (unsigned short*)alloc((size_t)N_NODES * 256 * 2);
    unsigned short* P1h = (unsigned short*)alloc((size_t)N_NODES * 256 * 2);
    unsigned short* P1l = (unsigned short*)alloc((size_t)N_NODES * 256 * 2);
    unsigned short* P2h = (unsigned short*)alloc((size_t)N_NODES * 256 * 2);
    unsigned short* P2l = (unsigned short*)alloc((size_t)N_NODES * 256 * 2);
    float* evals   = (float*)alloc((size_t)N_EDGES * 4);
    int* deg       = (int*)alloc((size_t)N_NODES * 4);
    int* off       = (int*)alloc((size_t)(N_NODES + 1) * 4);
    int* cursor    = (int*)alloc((size_t)N_NODES * 4);
    int* csr_src   = (int*)alloc((size_t)N_EDGES * 4);

    struct WP { unsigned short *h, *l; };
    auto wpair = [&](int n) -> WP {
        WP w; w.h = (unsigned short*)alloc((size_t)n * 2);
        w.l = (unsigned short*)alloc((size_t)n * 2); return w;
    };
    WP w_pre = wpair(256 * 128);
    WP w_c1l = wpair(256 * 256), w_c1r = wpair(256 * 256);
    WP w_c2l = wpair(256 * 256), w_c2r = wpair(256 * 256);
    WP w_c3l = wpair(128 * 256), w_c3r = wpair(128 * 256);
    WP w_h1  = wpair(256 * 256), w_h2 = wpair(256 * 256);
    WP w_oo  = wpair(128 * 128);

    if (used > ws_size) return;  // loud failure rather than silent corruption

    const int EB = (N_EDGES + 255) / 256;
    const int MB = (N_NODES + 127) / 128;  // 196

    // CSR build
    (void)hipMemsetAsync(deg, 0, N_NODES * sizeof(int), stream);
    hist_kernel<<<EB, 256, 0, stream>>>(dst, deg, N_EDGES);
    scan_kernel<<<1, 1024, 0, stream>>>(deg, off, cursor, N_NODES);
    scatter_kernel<<<EB, 256, 0, stream>>>(src, dst, cursor, csr_src, N_EDGES);

    // conversions
    auto cvt = [&](const float* s, WP w, int n) {
        convert_kernel<<<(n + 255) / 256, 256, 0, stream>>>(s, w.h, w.l, n);
    };
    convert_kernel<<<((N_NODES * 128) + 255) / 256, 256, 0, stream>>>(x, P0h, P0l, N_NODES * 128);
    cvt(prelin_w, w_pre, 256 * 128);
    cvt(conv1_lw, w_c1l, 256 * 256);  cvt(conv1_rw, w_c1r, 256 * 256);
    cvt(conv2_lw, w_c2l, 256 * 256);  cvt(conv2_rw, w_c2r, 256 * 256);
    cvt(conv3_lw, w_c3l, 128 * 256);  cvt(conv3_rw, w_c3r, 128 * 256);
    cvt(hh1_w,   w_h1, 256 * 256);    cvt(hh2_w,   w_h2, 256 * 256);
    cvt(oo_w,    w_oo, 128 * 128);

    // prelin: h1 = relu(x W^T + b) -> bufF(f32) + P1(pair)
    gemm_mfma_kernel<<<dim3(MB, 2), 256, 0, stream>>>(
        P0h, P0l, w_pre.h, w_pre.l, nullptr, nullptr, nullptr, nullptr,
        prelin_b, bufF, P1h, P1l, N_NODES, 128, 256, ACT_RELU);

    // conv1 + hh1
    sage_mean_kernel<<<N_NODES, 256, 0, stream>>>(bufF, off, csr_src, P2h, P2l);
    gemm_mfma_kernel<<<dim3(MB, 2), 256, 0, stream>>>(
        P2h, P2l, w_c1l.h, w_c1l.l, P1h, P1l, w_c1r.h, w_c1r.l,
        conv1_lb, nullptr, P0h, P0l, N_NODES, 256, 256, ACT_RELU);
    gemm_mfma_kernel<<<dim3(MB, 2), 256, 0, stream>>>(
        P0h, P0l, w_h1.h, w_h1.l, nullptr, nullptr, nullptr, nullptr,
        hh1_b, bufF, P1h, P1l, N_NODES, 256, 256, ACT_LEAKY);

    // conv2 + hh2
    sage_mean_kernel<<<N_NODES, 256, 0, stream>>>(bufF, off, csr_src, P2h, P2l);
    gemm_mfma_kernel<<<dim3(MB, 2), 256, 0, stream>>>(
        P2h, P2l, w_c2l.h, w_c2l.l, P1h, P1l, w_c2r.h, w_c2r.l,
        conv2_lb, nullptr, P0h, P0l, N_NODES, 256, 256, ACT_RELU);
    gemm_mfma_kernel<<<dim3(MB, 2), 256, 0, stream>>>(
        P0h, P0l, w_h2.h, w_h2.l, nullptr, nullptr, nullptr, nullptr,
        hh2_b, bufF, P1h, P1l, N_NODES, 256, 256, ACT_LEAKY);

    // conv3 (O=128) + oo
    sage_mean_kernel<<<N_NODES, 256, 0, stream>>>(bufF, off, csr_src, P2h, P2l);
    gemm_mfma_kernel<<<dim3(MB, 1), 256, 0, stream>>>(
        P2h, P2l, w_c3l.h, w_c3l.l, P1h, P1l, w_c3r.h, w_c3r.l,
        conv3_lb, nullptr, P0h, P0l, N_NODES, 256, 128, ACT_RELU);
    gemm_mfma_kernel<<<dim3(MB, 1), 256, 0, stream>>>(
        P0h, P0l, w_oo.h, w_oo.l, nullptr, nullptr, nullptr, nullptr,
        oo_b, bufF, nullptr, nullptr, N_NODES, 128, 128, ACT_LEAKY);

    // edge MLP + 48-group mean
    edge_kernel<<<EB, 256, 0, stream>>>(bufF, src, dst, edge_attr,
                                        lin96_w, lin96_b, lin32_w, lin32_b,
                                        evals, N_EDGES);
    const int G = N_EDGES / 48;
    group_mean_kernel<<<(G + 255) / 256, 256, 0, stream>>>(evals, (float*)d_out, G);
}

// Round 4
// 629.929 us; speedup vs baseline: 2.6644x; 1.3776x over previous
//
#include <hip/hip_runtime.h>
#include <hip/hip_bf16.h>

#define N_NODES 25000
#define N_EDGES 600000
#define ACT_NONE 0
#define ACT_RELU 1
#define ACT_LEAKY 2

typedef __bf16 bf16x8 __attribute__((ext_vector_type(8)));
typedef float f32x4 __attribute__((ext_vector_type(4)));
typedef unsigned short u16x8 __attribute__((ext_vector_type(8)));
typedef unsigned short u16x4 __attribute__((ext_vector_type(4)));

__device__ __forceinline__ unsigned short f2bf(float x) {
    union { float f; unsigned int u; } v; v.f = x;
    unsigned int r = (v.u + 0x7fffu + ((v.u >> 16) & 1u)) >> 16;
    return (unsigned short)r;
}
__device__ __forceinline__ float bf2f(unsigned short b) {
    union { float f; unsigned int u; } v; v.u = ((unsigned int)b) << 16;
    return v.f;
}

// ---------------------------------------------------------------------------
// CSR construction
// ---------------------------------------------------------------------------
__global__ __launch_bounds__(256) void hist_kernel(const int* __restrict__ dst,
                                                   int* __restrict__ deg, int E) {
    int e = blockIdx.x * 256 + threadIdx.x;
    if (e < E) atomicAdd(&deg[dst[e]], 1);
}

__global__ __launch_bounds__(1024) void scan_kernel(const int* __restrict__ deg,
                                                    int* __restrict__ off,
                                                    int* __restrict__ cursor, int n) {
    __shared__ int s[1024];
    int t = threadIdx.x;
    int carry = 0;
    for (int base = 0; base < n; base += 1024) {
        int v = (base + t < n) ? deg[base + t] : 0;
        s[t] = v;
        __syncthreads();
        #pragma unroll
        for (int d = 1; d < 1024; d <<= 1) {
            int x = (t >= d) ? s[t - d] : 0;
            __syncthreads();
            s[t] += x;
            __syncthreads();
        }
        int excl = s[t] - v;
        if (base + t < n) {
            off[base + t] = carry + excl;
            cursor[base + t] = carry + excl;
        }
        int total = s[1023];
        __syncthreads();
        carry += total;
    }
    if (t == 0) off[n] = carry;
}

__global__ __launch_bounds__(256) void scatter_kernel(const int* __restrict__ src,
                                                      const int* __restrict__ dst,
                                                      int* __restrict__ cursor,
                                                      int* __restrict__ csr_src, int E) {
    int e = blockIdx.x * 256 + threadIdx.x;
    if (e < E) {
        int d = dst[e];
        int pos = atomicAdd(&cursor[d], 1);
        csr_src[pos] = src[e];
    }
}

// ---------------------------------------------------------------------------
// fp32 -> bf16 hi/lo pair conversion
// ---------------------------------------------------------------------------
__global__ __launch_bounds__(256) void convert_kernel(const float* __restrict__ src,
                                                      unsigned short* __restrict__ hi,
                                                      unsigned short* __restrict__ lo, int n) {
    int i = blockIdx.x * 256 + threadIdx.x;
    if (i < n) {
        float x = src[i];
        unsigned short h = f2bf(x);
        hi[i] = h;
        lo[i] = f2bf(x - bf2f(h));
    }
}

// ---------------------------------------------------------------------------
// SAGE mean aggregation: wave per node, lane = 4 channels (float4), unroll x2
// outputs bf16 hi/lo pairs
// ---------------------------------------------------------------------------
__global__ __launch_bounds__(256) void sage_mean_kernel(const float* __restrict__ h,
                                                        const int* __restrict__ off,
                                                        const int* __restrict__ csr_src,
                                                        unsigned short* __restrict__ mh,
                                                        unsigned short* __restrict__ ml) {
    int node = blockIdx.x * 4 + (threadIdx.x >> 6);
    if (node >= N_NODES) return;
    int lane = threadIdx.x & 63;
    int s0 = off[node], s1 = off[node + 1];
    f32x4 acc0 = {0.f, 0.f, 0.f, 0.f}, acc1 = {0.f, 0.f, 0.f, 0.f};
    int e = s0;
    for (; e + 1 < s1; e += 2) {
        int sA = csr_src[e];
        int sB = csr_src[e + 1];
        f32x4 va = *(const f32x4*)&h[(long)sA * 256 + lane * 4];
        f32x4 vb = *(const f32x4*)&h[(long)sB * 256 + lane * 4];
        acc0 += va;
        acc1 += vb;
    }
    if (e < s1) {
        int sA = csr_src[e];
        acc0 += *(const f32x4*)&h[(long)sA * 256 + lane * 4];
    }
    float inv = 1.0f / fmaxf((float)(s1 - s0), 1.0f);
    f32x4 m = (acc0 + acc1) * inv;
    u16x4 hb, lb;
    #pragma unroll
    for (int j = 0; j < 4; ++j) {
        unsigned short hv = f2bf(m[j]);
        hb[j] = hv;
        lb[j] = f2bf(m[j] - bf2f(hv));
    }
    long base = (long)node * 256 + lane * 4;
    *(u16x4*)&mh[base] = hb;
    *(u16x4*)&ml[base] = lb;
}

// ---------------------------------------------------------------------------
// MFMA split-bf16 dual GEMM: C[M,O] = act(A1·W1^T (+ A2·W2^T) + bias)
// A,W given as bf16 hi/lo pairs. acc += hi*hi + hi*lo + lo*hi (3-pass).
// Tile 128x128, BK=32, 256 threads (4 waves, 2x2 of 64x64).
// ---------------------------------------------------------------------------
__global__ __launch_bounds__(256, 2) void gemm_mfma_kernel(
    const unsigned short* __restrict__ A1h, const unsigned short* __restrict__ A1l,
    const unsigned short* __restrict__ W1h, const unsigned short* __restrict__ W1l,
    const unsigned short* __restrict__ A2h, const unsigned short* __restrict__ A2l,
    const unsigned short* __restrict__ W2h, const unsigned short* __restrict__ W2l,
    const float* __restrict__ bias,
    float* __restrict__ Cf, unsigned short* __restrict__ Ch, unsigned short* __restrict__ Cl,
    int M, int K, int O, int act)
{
    __shared__ unsigned short sAh[128][40];
    __shared__ unsigned short sAl[128][40];
    __shared__ unsigned short sWh[128][40];
    __shared__ unsigned short sWl[128][40];

    int tid = threadIdx.x;
    int row0 = blockIdx.x * 128;
    int col0 = blockIdx.y * 128;
    int wid = tid >> 6, lane = tid & 63;
    int wm = (wid >> 1) * 64, wo = (wid & 1) * 64;
    int fr = lane & 15, kb = (lane >> 4) * 8;

    f32x4 acc[4][4] = {};

    for (int pass = 0; pass < 2; ++pass) {
        const unsigned short* Ah = pass ? A2h : A1h;
        const unsigned short* Al = pass ? A2l : A1l;
        const unsigned short* Wh = pass ? W2h : W1h;
        const unsigned short* Wl = pass ? W2l : W1l;
        if (Ah == nullptr) continue;
        for (int k0 = 0; k0 < K; k0 += 32) {
            #pragma unroll
            for (int i = 0; i < 2; ++i) {
                int chunk = tid + i * 256;      // 0..511
                int r = chunk >> 2;             // 0..127
                int cq = (chunk & 3) * 8;       // 0,8,16,24
                int ga = row0 + r;
                u16x8 zero = (u16x8)0;
                u16x8 va_h = (ga < M) ? *(const u16x8*)&Ah[(long)ga * K + k0 + cq] : zero;
                u16x8 va_l = (ga < M) ? *(const u16x8*)&Al[(long)ga * K + k0 + cq] : zero;
                u16x8 vw_h = *(const u16x8*)&Wh[(long)(col0 + r) * K + k0 + cq];
                u16x8 vw_l = *(const u16x8*)&Wl[(long)(col0 + r) * K + k0 + cq];
                *(u16x8*)&sAh[r][cq] = va_h;
                *(u16x8*)&sAl[r][cq] = va_l;
                *(u16x8*)&sWh[r][cq] = vw_h;
                *(u16x8*)&sWl[r][cq] = vw_l;
            }
            __syncthreads();
            bf16x8 ah[4], al[4], bh[4], bl[4];
            #pragma unroll
            for (int i = 0; i < 4; ++i) {
                ah[i] = *(const bf16x8*)&sAh[wm + i * 16 + fr][kb];
                al[i] = *(const bf16x8*)&sAl[wm + i * 16 + fr][kb];
                bh[i] = *(const bf16x8*)&sWh[wo + i * 16 + fr][kb];
                bl[i] = *(const bf16x8*)&sWl[wo + i * 16 + fr][kb];
            }
            #pragma unroll
            for (int i = 0; i < 4; ++i) {
                #pragma unroll
                for (int j = 0; j < 4; ++j) {
                    acc[i][j] = __builtin_amdgcn_mfma_f32_16x16x32_bf16(ah[i], bh[j], acc[i][j], 0, 0, 0);
                    acc[i][j] = __builtin_amdgcn_mfma_f32_16x16x32_bf16(ah[i], bl[j], acc[i][j], 0, 0, 0);
                    acc[i][j] = __builtin_amdgcn_mfma_f32_16x16x32_bf16(al[i], bh[j], acc[i][j], 0, 0, 0);
                }
            }
            __syncthreads();
        }
    }

    // epilogue: C/D layout col=lane&15, row=(lane>>4)*4+reg  [m89-verified]
    int rgrp = (lane >> 4) * 4;
    int cl_ = lane & 15;
    #pragma unroll
    for (int i = 0; i < 4; ++i) {
        #pragma unroll
        for (int j = 0; j < 4; ++j) {
            int gcol = col0 + wo + j * 16 + cl_;
            float bv = bias[gcol];
            #pragma unroll
            for (int r = 0; r < 4; ++r) {
                int grow = row0 + wm + i * 16 + rgrp + r;
                if (grow < M) {
                    float v = acc[i][j][r] + bv;
                    if (act == ACT_RELU)       v = fmaxf(v, 0.0f);
                    else if (act == ACT_LEAKY) v = (v > 0.0f) ? v : 0.01f * v;
                    long idx = (long)grow * O + gcol;
                    if (Cf) Cf[idx] = v;
                    if (Ch) {
                        unsigned short hbits = f2bf(v);
                        Ch[idx] = hbits;
                        Cl[idx] = f2bf(v - bf2f(hbits));
                    }
                }
            }
        }
    }
}

// ---------------------------------------------------------------------------
// Per-node edge-MLP dot products: nodeDot[n] = {dL96, dR96, dL32, dR32}
//   dL96 = sum_{c<96} h[n][c]*w96[c]       dR96 = sum_{c<96} h[n][c]*w96[96+c]
//   dL32 = sum_{k<32} h[n][96+k]*w32[k]    dR32 = sum_{k<32} h[n][96+k]*w32[32+k]
// one wave per node (h row = 128 floats, lane covers c=lane and c=lane+64)
// ---------------------------------------------------------------------------
__global__ __launch_bounds__(256) void node_dots_kernel(const float* __restrict__ h,
                                                        const float* __restrict__ w96,
                                                        const float* __restrict__ w32,
                                                        float* __restrict__ nodeDot) {
    int node = blockIdx.x * 4 + (threadIdx.x >> 6);
    if (node >= N_NODES) return;
    int lane = threadIdx.x & 63;
    const float* row = h + (long)node * 128;
    float h0 = row[lane];        // c = lane in [0,64): 96-part
    float h1 = row[64 + lane];   // c2 = 64+lane in [64,128)
    float pL96 = h0 * w96[lane];
    float pR96 = h0 * w96[96 + lane];
    float pL32 = 0.0f, pR32 = 0.0f;
    if (lane < 32) {
        pL96 += h1 * w96[64 + lane];
        pR96 += h1 * w96[160 + lane];
    } else {
        int k = lane - 32;
        pL32 = h1 * w32[k];
        pR32 = h1 * w32[32 + k];
    }
    #pragma unroll
    for (int m = 32; m > 0; m >>= 1) {
        pL96 += __shfl_xor(pL96, m);
        pR96 += __shfl_xor(pR96, m);
        pL32 += __shfl_xor(pL32, m);
        pR32 += __shfl_xor(pR32, m);
    }
    if (lane == 0) {
        f32x4 v = {pL96, pR96, pL32, pR32};
        *(f32x4*)&nodeDot[(long)node * 4] = v;
    }
}

// ---------------------------------------------------------------------------
// Per-edge affinity from node dots
// ---------------------------------------------------------------------------
__global__ __launch_bounds__(256) void edge_aff_kernel(const float* __restrict__ nodeDot,
                                                       const int* __restrict__ src,
                                                       const int* __restrict__ dst,
                                                       const float* __restrict__ eattr,
                                                       const float* __restrict__ b96,
                                                       const float* __restrict__ b32,
                                                       float* __restrict__ vals, int E) {
    int e = blockIdx.x * 256 + threadIdx.x;
    if (e >= E) return;
    f32x4 a = *(const f32x4*)&nodeDot[(long)src[e] * 4];
    f32x4 b = *(const f32x4*)&nodeDot[(long)dst[e] * 4];
    float f96  = fmaxf(a[0] + b[1] + b96[0], 0.0f);
    float f32v = fmaxf(a[2] + b[3] + b32[0], 0.0f);
    vals[e] = f96 * eattr[e] + f32v;
}

__global__ __launch_bounds__(256) void group_mean_kernel(const float* __restrict__ vals,
                                                         float* __restrict__ out, int G) {
    int g = blockIdx.x * 256 + threadIdx.x;
    if (g >= G) return;
    float s = 0.0f;
    #pragma unroll
    for (int k = 0; k < 48; ++k) s += vals[g * 48 + k];
    out[g] = s * (1.0f / 48.0f);
}

// ---------------------------------------------------------------------------
extern "C" void kernel_launch(void* const* d_in, const int* in_sizes, int n_in,
                              void* d_out, int out_size, void* d_ws, size_t ws_size,
                              hipStream_t stream) {
    const float* x         = (const float*)d_in[0];
    const int*   edge_idx  = (const int*)d_in[1];
    const float* edge_attr = (const float*)d_in[2];
    const float* prelin_w  = (const float*)d_in[4];
    const float* prelin_b  = (const float*)d_in[5];
    const float* conv1_lw  = (const float*)d_in[6];
    const float* conv1_lb  = (const float*)d_in[7];
    const float* conv1_rw  = (const float*)d_in[8];
    const float* conv2_lw  = (const float*)d_in[9];
    const float* conv2_lb  = (const float*)d_in[10];
    const float* conv2_rw  = (const float*)d_in[11];
    const float* conv3_lw  = (const float*)d_in[12];
    const float* conv3_lb  = (const float*)d_in[13];
    const float* conv3_rw  = (const float*)d_in[14];
    const float* hh1_w     = (const float*)d_in[15];
    const float* hh1_b     = (const float*)d_in[16];
    const float* hh2_w     = (const float*)d_in[17];
    const float* hh2_b     = (const float*)d_in[18];
    const float* oo_w      = (const float*)d_in[19];
    const float* oo_b      = (const float*)d_in[20];
    const float* lin96_w   = (const float*)d_in[21];
    const float* lin96_b   = (const float*)d_in[22];
    const float* lin32_w   = (const float*)d_in[23];
    const float* lin32_b   = (const float*)d_in[24];

    const int* src = edge_idx;
    const int* dst = edge_idx + N_EDGES;

    // ---- workspace carve-up ----
    char* wsp = (char*)d_ws;
    size_t used = 0;
    auto alloc = [&](size_t bytes) -> char* {
        char* r = wsp;
        size_t pad = (bytes + 255) & ~(size_t)255;
        wsp += pad; used += pad;
        return r;
    };
    float* bufF = (float*)alloc((size_t)N_NODES * 256 * 4);
    unsigned short* P0h = (unsigned short*)alloc((size_t)N_NODES * 256 * 2);
    unsigned short* P0l = (unsigned short*)alloc((size_t)N_NODES * 256 * 2);
    unsigned short* P1h = (unsigned short*)alloc((size_t)N_NODES * 256 * 2);
    unsigned short* P1l = (unsigned short*)alloc((size_t)N_NODES * 256 * 2);
    unsigned short* P2h = (unsigned short*)alloc((size_t)N_NODES * 256 * 2);
    unsigned short* P2l = (unsigned short*)alloc((size_t)N_NODES * 256 * 2);
    float* evals   = (float*)alloc((size_t)N_EDGES * 4);
    float* nodeDot = (float*)alloc((size_t)N_NODES * 4 * 4);
    int* deg       = (int*)alloc((size_t)N_NODES * 4);
    int* off       = (int*)alloc((size_t)(N_NODES + 1) * 4);
    int* cursor    = (int*)alloc((size_t)N_NODES * 4);
    int* csr_src   = (int*)alloc((size_t)N_EDGES * 4);

    struct WP { unsigned short *h, *l; };
    auto wpair = [&](int n) -> WP {
        WP w; w.h = (unsigned short*)alloc((size_t)n * 2);
        w.l = (unsigned short*)alloc((size_t)n * 2); return w;
    };
    WP w_pre = wpair(256 * 128);
    WP w_c1l = wpair(256 * 256), w_c1r = wpair(256 * 256);
    WP w_c2l = wpair(256 * 256), w_c2r = wpair(256 * 256);
    WP w_c3l = wpair(128 * 256), w_c3r = wpair(128 * 256);
    WP w_h1  = wpair(256 * 256), w_h2 = wpair(256 * 256);
    WP w_oo  = wpair(128 * 128);

    if (used > ws_size) return;  // loud failure rather than silent corruption

    const int EB = (N_EDGES + 255) / 256;
    const int MB = (N_NODES + 127) / 128;  // 196
    const int NB4 = (N_NODES + 3) / 4;     // 6250 (wave-per-node kernels)

    // CSR build
    (void)hipMemsetAsync(deg, 0, N_NODES * sizeof(int), stream);
    hist_kernel<<<EB, 256, 0, stream>>>(dst, deg, N_EDGES);
    scan_kernel<<<1, 1024, 0, stream>>>(deg, off, cursor, N_NODES);
    scatter_kernel<<<EB, 256, 0, stream>>>(src, dst, cursor, csr_src, N_EDGES);

    // conversions
    auto cvt = [&](const float* s, WP w, int n) {
        convert_kernel<<<(n + 255) / 256, 256, 0, stream>>>(s, w.h, w.l, n);
    };
    convert_kernel<<<((N_NODES * 128) + 255) / 256, 256, 0, stream>>>(x, P0h, P0l, N_NODES * 128);
    cvt(prelin_w, w_pre, 256 * 128);
    cvt(conv1_lw, w_c1l, 256 * 256);  cvt(conv1_rw, w_c1r, 256 * 256);
    cvt(conv2_lw, w_c2l, 256 * 256);  cvt(conv2_rw, w_c2r, 256 * 256);
    cvt(conv3_lw, w_c3l, 128 * 256);  cvt(conv3_rw, w_c3r, 128 * 256);
    cvt(hh1_w,   w_h1, 256 * 256);    cvt(hh2_w,   w_h2, 256 * 256);
    cvt(oo_w,    w_oo, 128 * 128);

    // prelin: h1 = relu(x W^T + b) -> bufF(f32) + P1(pair)
    gemm_mfma_kernel<<<dim3(MB, 2), 256, 0, stream>>>(
        P0h, P0l, w_pre.h, w_pre.l, nullptr, nullptr, nullptr, nullptr,
        prelin_b, bufF, P1h, P1l, N_NODES, 128, 256, ACT_RELU);

    // conv1 + hh1
    sage_mean_kernel<<<NB4, 256, 0, stream>>>(bufF, off, csr_src, P2h, P2l);
    gemm_mfma_kernel<<<dim3(MB, 2), 256, 0, stream>>>(
        P2h, P2l, w_c1l.h, w_c1l.l, P1h, P1l, w_c1r.h, w_c1r.l,
        conv1_lb, nullptr, P0h, P0l, N_NODES, 256, 256, ACT_RELU);
    gemm_mfma_kernel<<<dim3(MB, 2), 256, 0, stream>>>(
        P0h, P0l, w_h1.h, w_h1.l, nullptr, nullptr, nullptr, nullptr,
        hh1_b, bufF, P1h, P1l, N_NODES, 256, 256, ACT_LEAKY);

    // conv2 + hh2
    sage_mean_kernel<<<NB4, 256, 0, stream>>>(bufF, off, csr_src, P2h, P2l);
    gemm_mfma_kernel<<<dim3(MB, 2), 256, 0, stream>>>(
        P2h, P2l, w_c2l.h, w_c2l.l, P1h, P1l, w_c2r.h, w_c2r.l,
        conv2_lb, nullptr, P0h, P0l, N_NODES, 256, 256, ACT_RELU);
    gemm_mfma_kernel<<<dim3(MB, 2), 256, 0, stream>>>(
        P0h, P0l, w_h2.h, w_h2.l, nullptr, nullptr, nullptr, nullptr,
        hh2_b, bufF, P1h, P1l, N_NODES, 256, 256, ACT_LEAKY);

    // conv3 (O=128) + oo
    sage_mean_kernel<<<NB4, 256, 0, stream>>>(bufF, off, csr_src, P2h, P2l);
    gemm_mfma_kernel<<<dim3(MB, 1), 256, 0, stream>>>(
        P2h, P2l, w_c3l.h, w_c3l.l, P1h, P1l, w_c3r.h, w_c3r.l,
        conv3_lb, nullptr, P0h, P0l, N_NODES, 256, 128, ACT_RELU);
    gemm_mfma_kernel<<<dim3(MB, 1), 256, 0, stream>>>(
        P0h, P0l, w_oo.h, w_oo.l, nullptr, nullptr, nullptr, nullptr,
        oo_b, bufF, nullptr, nullptr, N_NODES, 128, 128, ACT_LEAKY);

    // per-node dots -> per-edge affinity -> 48-group mean
    node_dots_kernel<<<NB4, 256, 0, stream>>>(bufF, lin96_w, lin32_w, nodeDot);
    edge_aff_kernel<<<EB, 256, 0, stream>>>(nodeDot, src, dst, edge_attr,
                                            lin96_b, lin32_b, evals, N_EDGES);
    const int G = N_EDGES / 48;
    group_mean_kernel<<<(G + 255) / 256, 256, 0, stream>>>(evals, (float*)d_out, G);
}

// Round 5
// 598.138 us; speedup vs baseline: 2.8060x; 1.0531x over previous
//
#include <hip/hip_runtime.h>
#include <hip/hip_bf16.h>

#define N_NODES 25000
#define N_EDGES 600000
#define ACT_NONE 0
#define ACT_RELU 1
#define ACT_LEAKY 2

typedef __bf16 bf16x8 __attribute__((ext_vector_type(8)));
typedef float f32x4 __attribute__((ext_vector_type(4)));
typedef unsigned short u16x8 __attribute__((ext_vector_type(8)));
typedef unsigned short u16x4 __attribute__((ext_vector_type(4)));

__device__ __forceinline__ unsigned short f2bf(float x) {
    union { float f; unsigned int u; } v; v.f = x;
    unsigned int r = (v.u + 0x7fffu + ((v.u >> 16) & 1u)) >> 16;
    return (unsigned short)r;
}
__device__ __forceinline__ float bf2f(unsigned short b) {
    union { float f; unsigned int u; } v; v.u = ((unsigned int)b) << 16;
    return v.f;
}

// ---------------------------------------------------------------------------
// CSR construction
// ---------------------------------------------------------------------------
__global__ __launch_bounds__(256) void hist_kernel(const int* __restrict__ dst,
                                                   int* __restrict__ deg, int E) {
    int e = blockIdx.x * 256 + threadIdx.x;
    if (e < E) atomicAdd(&deg[dst[e]], 1);
}

// wave-shuffle scan: 3 barriers per 1024-chunk (was ~20)
__global__ __launch_bounds__(1024) void scan_kernel(const int* __restrict__ deg,
                                                    int* __restrict__ off,
                                                    int* __restrict__ cursor, int n) {
    __shared__ int wsum[16];
    int t = threadIdx.x, w = t >> 6, l = t & 63;
    int carry = 0;
    for (int base = 0; base < n; base += 1024) {
        int v = (base + t < n) ? deg[base + t] : 0;
        int x = v;
        #pragma unroll
        for (int d = 1; d < 64; d <<= 1) {
            int y = __shfl_up(x, d);
            if (l >= d) x += y;
        }
        if (l == 63) wsum[w] = x;
        __syncthreads();
        if (w == 0 && l < 16) {
            int s = wsum[l];
            #pragma unroll
            for (int d = 1; d < 16; d <<= 1) {
                int y = __shfl_up(s, d);
                if (l >= d) s += y;
            }
            wsum[l] = s;
        }
        __syncthreads();
        int woff = (w > 0) ? wsum[w - 1] : 0;
        int excl = x + woff - v;
        if (base + t < n) {
            off[base + t] = carry + excl;
            cursor[base + t] = carry + excl;
        }
        int total = wsum[15];
        __syncthreads();
        carry += total;
    }
    if (t == 0) off[n] = carry;
}

__global__ __launch_bounds__(256) void scatter_kernel(const int* __restrict__ src,
                                                      const int* __restrict__ dst,
                                                      int* __restrict__ cursor,
                                                      int* __restrict__ csr_src, int E) {
    int e = blockIdx.x * 256 + threadIdx.x;
    if (e < E) {
        int d = dst[e];
        int pos = atomicAdd(&cursor[d], 1);
        csr_src[pos] = src[e];
    }
}

// ---------------------------------------------------------------------------
// fp32 -> bf16 hi/lo pair conversion (single large array)
// ---------------------------------------------------------------------------
__global__ __launch_bounds__(256) void convert_kernel(const float* __restrict__ src,
                                                      unsigned short* __restrict__ hi,
                                                      unsigned short* __restrict__ lo, int n) {
    int i = blockIdx.x * 256 + threadIdx.x;
    if (i < n) {
        float x = src[i];
        unsigned short h = f2bf(x);
        hi[i] = h;
        lo[i] = f2bf(x - bf2f(h));
    }
}

// batched conversion for the 10 weight matrices: blockIdx.y = segment
struct CvtBatch {
    const float* src[10];
    unsigned short* hi[10];
    unsigned short* lo[10];
    int count[10];
};
__global__ __launch_bounds__(256) void convert_batch_kernel(CvtBatch b) {
    int seg = blockIdx.y;
    int n = b.count[seg];
    int i = blockIdx.x * 256 + threadIdx.x;
    if (i >= n) return;
    float x = b.src[seg][i];
    unsigned short h = f2bf(x);
    b.hi[seg][i] = h;
    b.lo[seg][i] = f2bf(x - bf2f(h));
}

// ---------------------------------------------------------------------------
// SAGE mean aggregation: wave per node, lane = 4 channels (float4), 4-deep ILP
// ---------------------------------------------------------------------------
__global__ __launch_bounds__(256) void sage_mean_kernel(const float* __restrict__ h,
                                                        const int* __restrict__ off,
                                                        const int* __restrict__ csr_src,
                                                        unsigned short* __restrict__ mh,
                                                        unsigned short* __restrict__ ml) {
    int node = blockIdx.x * 4 + (threadIdx.x >> 6);
    if (node >= N_NODES) return;
    int lane = threadIdx.x & 63;
    int s0 = off[node], s1 = off[node + 1];
    f32x4 acc0 = {0.f, 0.f, 0.f, 0.f}, acc1 = {0.f, 0.f, 0.f, 0.f};
    f32x4 acc2 = {0.f, 0.f, 0.f, 0.f}, acc3 = {0.f, 0.f, 0.f, 0.f};
    long loff = (long)lane * 4;
    int e = s0;
    for (; e + 4 <= s1; e += 4) {
        int iA = csr_src[e];
        int iB = csr_src[e + 1];
        int iC = csr_src[e + 2];
        int iD = csr_src[e + 3];
        f32x4 va = *(const f32x4*)&h[(long)iA * 256 + loff];
        f32x4 vb = *(const f32x4*)&h[(long)iB * 256 + loff];
        f32x4 vc = *(const f32x4*)&h[(long)iC * 256 + loff];
        f32x4 vd = *(const f32x4*)&h[(long)iD * 256 + loff];
        acc0 += va; acc1 += vb; acc2 += vc; acc3 += vd;
    }
    for (; e < s1; ++e) {
        int iA = csr_src[e];
        acc0 += *(const f32x4*)&h[(long)iA * 256 + loff];
    }
    float inv = 1.0f / fmaxf((float)(s1 - s0), 1.0f);
    f32x4 m = ((acc0 + acc1) + (acc2 + acc3)) * inv;
    u16x4 hb, lb;
    #pragma unroll
    for (int j = 0; j < 4; ++j) {
        unsigned short hv = f2bf(m[j]);
        hb[j] = hv;
        lb[j] = f2bf(m[j] - bf2f(hv));
    }
    long base = (long)node * 256 + loff;
    *(u16x4*)&mh[base] = hb;
    *(u16x4*)&ml[base] = lb;
}

// ---------------------------------------------------------------------------
// MFMA split-bf16 dual GEMM: C[M,O] = act(A1·W1^T (+ A2·W2^T) + bias)
// A,W given as bf16 hi/lo pairs. acc += hi*hi + hi*lo + lo*hi (3-pass).
// Tile 128x128, BK=32, 256 threads (4 waves, 2x2 of 64x64).
// ---------------------------------------------------------------------------
__global__ __launch_bounds__(256, 2) void gemm_mfma_kernel(
    const unsigned short* __restrict__ A1h, const unsigned short* __restrict__ A1l,
    const unsigned short* __restrict__ W1h, const unsigned short* __restrict__ W1l,
    const unsigned short* __restrict__ A2h, const unsigned short* __restrict__ A2l,
    const unsigned short* __restrict__ W2h, const unsigned short* __restrict__ W2l,
    const float* __restrict__ bias,
    float* __restrict__ Cf, unsigned short* __restrict__ Ch, unsigned short* __restrict__ Cl,
    int M, int K, int O, int act)
{
    __shared__ unsigned short sAh[128][40];
    __shared__ unsigned short sAl[128][40];
    __shared__ unsigned short sWh[128][40];
    __shared__ unsigned short sWl[128][40];

    int tid = threadIdx.x;
    int row0 = blockIdx.x * 128;
    int col0 = blockIdx.y * 128;
    int wid = tid >> 6, lane = tid & 63;
    int wm = (wid >> 1) * 64, wo = (wid & 1) * 64;
    int fr = lane & 15, kb = (lane >> 4) * 8;

    f32x4 acc[4][4] = {};

    for (int pass = 0; pass < 2; ++pass) {
        const unsigned short* Ah = pass ? A2h : A1h;
        const unsigned short* Al = pass ? A2l : A1l;
        const unsigned short* Wh = pass ? W2h : W1h;
        const unsigned short* Wl = pass ? W2l : W1l;
        if (Ah == nullptr) continue;
        for (int k0 = 0; k0 < K; k0 += 32) {
            #pragma unroll
            for (int i = 0; i < 2; ++i) {
                int chunk = tid + i * 256;      // 0..511
                int r = chunk >> 2;             // 0..127
                int cq = (chunk & 3) * 8;       // 0,8,16,24
                int ga = row0 + r;
                u16x8 zero = (u16x8)0;
                u16x8 va_h = (ga < M) ? *(const u16x8*)&Ah[(long)ga * K + k0 + cq] : zero;
                u16x8 va_l = (ga < M) ? *(const u16x8*)&Al[(long)ga * K + k0 + cq] : zero;
                u16x8 vw_h = *(const u16x8*)&Wh[(long)(col0 + r) * K + k0 + cq];
                u16x8 vw_l = *(const u16x8*)&Wl[(long)(col0 + r) * K + k0 + cq];
                *(u16x8*)&sAh[r][cq] = va_h;
                *(u16x8*)&sAl[r][cq] = va_l;
                *(u16x8*)&sWh[r][cq] = vw_h;
                *(u16x8*)&sWl[r][cq] = vw_l;
            }
            __syncthreads();
            bf16x8 ah[4], al[4], bh[4], bl[4];
            #pragma unroll
            for (int i = 0; i < 4; ++i) {
                ah[i] = *(const bf16x8*)&sAh[wm + i * 16 + fr][kb];
                al[i] = *(const bf16x8*)&sAl[wm + i * 16 + fr][kb];
                bh[i] = *(const bf16x8*)&sWh[wo + i * 16 + fr][kb];
                bl[i] = *(const bf16x8*)&sWl[wo + i * 16 + fr][kb];
            }
            #pragma unroll
            for (int i = 0; i < 4; ++i) {
                #pragma unroll
                for (int j = 0; j < 4; ++j) {
                    acc[i][j] = __builtin_amdgcn_mfma_f32_16x16x32_bf16(ah[i], bh[j], acc[i][j], 0, 0, 0);
                    acc[i][j] = __builtin_amdgcn_mfma_f32_16x16x32_bf16(ah[i], bl[j], acc[i][j], 0, 0, 0);
                    acc[i][j] = __builtin_amdgcn_mfma_f32_16x16x32_bf16(al[i], bh[j], acc[i][j], 0, 0, 0);
                }
            }
            __syncthreads();
        }
    }

    // epilogue: C/D layout col=lane&15, row=(lane>>4)*4+reg  [m89-verified]
    int rgrp = (lane >> 4) * 4;
    int cl_ = lane & 15;
    #pragma unroll
    for (int i = 0; i < 4; ++i) {
        #pragma unroll
        for (int j = 0; j < 4; ++j) {
            int gcol = col0 + wo + j * 16 + cl_;
            float bv = bias[gcol];
            #pragma unroll
            for (int r = 0; r < 4; ++r) {
                int grow = row0 + wm + i * 16 + rgrp + r;
                if (grow < M) {
                    float v = acc[i][j][r] + bv;
                    if (act == ACT_RELU)       v = fmaxf(v, 0.0f);
                    else if (act == ACT_LEAKY) v = (v > 0.0f) ? v : 0.01f * v;
                    long idx = (long)grow * O + gcol;
                    if (Cf) Cf[idx] = v;
                    if (Ch) {
                        unsigned short hbits = f2bf(v);
                        Ch[idx] = hbits;
                        Cl[idx] = f2bf(v - bf2f(hbits));
                    }
                }
            }
        }
    }
}

// ---------------------------------------------------------------------------
// Per-node edge-MLP dot products: nodeDot[n] = {dL96, dR96, dL32, dR32}
// ---------------------------------------------------------------------------
__global__ __launch_bounds__(256) void node_dots_kernel(const float* __restrict__ h,
                                                        const float* __restrict__ w96,
                                                        const float* __restrict__ w32,
                                                        float* __restrict__ nodeDot) {
    int node = blockIdx.x * 4 + (threadIdx.x >> 6);
    if (node >= N_NODES) return;
    int lane = threadIdx.x & 63;
    const float* row = h + (long)node * 128;
    float h0 = row[lane];
    float h1 = row[64 + lane];
    float pL96 = h0 * w96[lane];
    float pR96 = h0 * w96[96 + lane];
    float pL32 = 0.0f, pR32 = 0.0f;
    if (lane < 32) {
        pL96 += h1 * w96[64 + lane];
        pR96 += h1 * w96[160 + lane];
    } else {
        int k = lane - 32;
        pL32 = h1 * w32[k];
        pR32 = h1 * w32[32 + k];
    }
    #pragma unroll
    for (int m = 32; m > 0; m >>= 1) {
        pL96 += __shfl_xor(pL96, m);
        pR96 += __shfl_xor(pR96, m);
        pL32 += __shfl_xor(pL32, m);
        pR32 += __shfl_xor(pR32, m);
    }
    if (lane == 0) {
        f32x4 v = {pL96, pR96, pL32, pR32};
        *(f32x4*)&nodeDot[(long)node * 4] = v;
    }
}

// ---------------------------------------------------------------------------
// Per-edge affinity from node dots
// ---------------------------------------------------------------------------
__global__ __launch_bounds__(256) void edge_aff_kernel(const float* __restrict__ nodeDot,
                                                       const int* __restrict__ src,
                                                       const int* __restrict__ dst,
                                                       const float* __restrict__ eattr,
                                                       const float* __restrict__ b96,
                                                       const float* __restrict__ b32,
                                                       float* __restrict__ vals, int E) {
    int e = blockIdx.x * 256 + threadIdx.x;
    if (e >= E) return;
    f32x4 a = *(const f32x4*)&nodeDot[(long)src[e] * 4];
    f32x4 b = *(const f32x4*)&nodeDot[(long)dst[e] * 4];
    float f96  = fmaxf(a[0] + b[1] + b96[0], 0.0f);
    float f32v = fmaxf(a[2] + b[3] + b32[0], 0.0f);
    vals[e] = f96 * eattr[e] + f32v;
}

__global__ __launch_bounds__(256) void group_mean_kernel(const float* __restrict__ vals,
                                                         float* __restrict__ out, int G) {
    int g = blockIdx.x * 256 + threadIdx.x;
    if (g >= G) return;
    float s = 0.0f;
    #pragma unroll
    for (int k = 0; k < 48; ++k) s += vals[g * 48 + k];
    out[g] = s * (1.0f / 48.0f);
}

// ---------------------------------------------------------------------------
extern "C" void kernel_launch(void* const* d_in, const int* in_sizes, int n_in,
                              void* d_out, int out_size, void* d_ws, size_t ws_size,
                              hipStream_t stream) {
    const float* x         = (const float*)d_in[0];
    const int*   edge_idx  = (const int*)d_in[1];
    const float* edge_attr = (const float*)d_in[2];
    const float* prelin_w  = (const float*)d_in[4];
    const float* prelin_b  = (const float*)d_in[5];
    const float* conv1_lw  = (const float*)d_in[6];
    const float* conv1_lb  = (const float*)d_in[7];
    const float* conv1_rw  = (const float*)d_in[8];
    const float* conv2_lw  = (const float*)d_in[9];
    const float* conv2_lb  = (const float*)d_in[10];
    const float* conv2_rw  = (const float*)d_in[11];
    const float* conv3_lw  = (const float*)d_in[12];
    const float* conv3_lb  = (const float*)d_in[13];
    const float* conv3_rw  = (const float*)d_in[14];
    const float* hh1_w     = (const float*)d_in[15];
    const float* hh1_b     = (const float*)d_in[16];
    const float* hh2_w     = (const float*)d_in[17];
    const float* hh2_b     = (const float*)d_in[18];
    const float* oo_w      = (const float*)d_in[19];
    const float* oo_b      = (const float*)d_in[20];
    const float* lin96_w   = (const float*)d_in[21];
    const float* lin96_b   = (const float*)d_in[22];
    const float* lin32_w   = (const float*)d_in[23];
    const float* lin32_b   = (const float*)d_in[24];

    const int* src = edge_idx;
    const int* dst = edge_idx + N_EDGES;

    // ---- workspace carve-up ----
    char* wsp = (char*)d_ws;
    size_t used = 0;
    auto alloc = [&](size_t bytes) -> char* {
        char* r = wsp;
        size_t pad = (bytes + 255) & ~(size_t)255;
        wsp += pad; used += pad;
        return r;
    };
    float* bufF = (float*)alloc((size_t)N_NODES * 256 * 4);
    unsigned short* P0h = (unsigned short*)alloc((size_t)N_NODES * 256 * 2);
    unsigned short* P0l = (unsigned short*)alloc((size_t)N_NODES * 256 * 2);
    unsigned short* P1h = (unsigned short*)alloc((size_t)N_NODES * 256 * 2);
    unsigned short* P1l = (unsigned short*)alloc((size_t)N_NODES * 256 * 2);
    unsigned short* P2h = (unsigned short*)alloc((size_t)N_NODES * 256 * 2);
    unsigned short* P2l = (unsigned short*)alloc((size_t)N_NODES * 256 * 2);
    float* evals   = (float*)alloc((size_t)N_EDGES * 4);
    float* nodeDot = (float*)alloc((size_t)N_NODES * 4 * 4);
    int* deg       = (int*)alloc((size_t)N_NODES * 4);
    int* off       = (int*)alloc((size_t)(N_NODES + 1) * 4);
    int* cursor    = (int*)alloc((size_t)N_NODES * 4);
    int* csr_src   = (int*)alloc((size_t)N_EDGES * 4);

    struct WP { unsigned short *h, *l; };
    auto wpair = [&](int n) -> WP {
        WP w; w.h = (unsigned short*)alloc((size_t)n * 2);
        w.l = (unsigned short*)alloc((size_t)n * 2); return w;
    };
    WP w_pre = wpair(256 * 128);
    WP w_c1l = wpair(256 * 256), w_c1r = wpair(256 * 256);
    WP w_c2l = wpair(256 * 256), w_c2r = wpair(256 * 256);
    WP w_c3l = wpair(128 * 256), w_c3r = wpair(128 * 256);
    WP w_h1  = wpair(256 * 256), w_h2 = wpair(256 * 256);
    WP w_oo  = wpair(128 * 128);

    if (used > ws_size) return;  // loud failure rather than silent corruption

    const int EB = (N_EDGES + 255) / 256;
    const int MB = (N_NODES + 127) / 128;  // 196
    const int NB4 = (N_NODES + 3) / 4;     // 6250 (wave-per-node kernels)

    // CSR build
    (void)hipMemsetAsync(deg, 0, N_NODES * sizeof(int), stream);
    hist_kernel<<<EB, 256, 0, stream>>>(dst, deg, N_EDGES);
    scan_kernel<<<1, 1024, 0, stream>>>(deg, off, cursor, N_NODES);
    scatter_kernel<<<EB, 256, 0, stream>>>(src, dst, cursor, csr_src, N_EDGES);

    // conversions: x separately, 10 weights in ONE batched launch
    convert_kernel<<<((N_NODES * 128) + 255) / 256, 256, 0, stream>>>(x, P0h, P0l, N_NODES * 128);
    CvtBatch cb;
    const float* wsrc[10] = {prelin_w, conv1_lw, conv1_rw, conv2_lw, conv2_rw,
                             conv3_lw, conv3_rw, hh1_w, hh2_w, oo_w};
    WP wdst[10] = {w_pre, w_c1l, w_c1r, w_c2l, w_c2r, w_c3l, w_c3r, w_h1, w_h2, w_oo};
    int wcnt[10] = {256 * 128, 256 * 256, 256 * 256, 256 * 256, 256 * 256,
                    128 * 256, 128 * 256, 256 * 256, 256 * 256, 128 * 128};
    for (int i = 0; i < 10; ++i) {
        cb.src[i] = wsrc[i]; cb.hi[i] = wdst[i].h; cb.lo[i] = wdst[i].l; cb.count[i] = wcnt[i];
    }
    convert_batch_kernel<<<dim3((65536 + 255) / 256, 10), 256, 0, stream>>>(cb);

    // prelin: h1 = relu(x W^T + b) -> bufF(f32) + P1(pair)
    gemm_mfma_kernel<<<dim3(MB, 2), 256, 0, stream>>>(
        P0h, P0l, w_pre.h, w_pre.l, nullptr, nullptr, nullptr, nullptr,
        prelin_b, bufF, P1h, P1l, N_NODES, 128, 256, ACT_RELU);

    // conv1 + hh1
    sage_mean_kernel<<<NB4, 256, 0, stream>>>(bufF, off, csr_src, P2h, P2l);
    gemm_mfma_kernel<<<dim3(MB, 2), 256, 0, stream>>>(
        P2h, P2l, w_c1l.h, w_c1l.l, P1h, P1l, w_c1r.h, w_c1r.l,
        conv1_lb, nullptr, P0h, P0l, N_NODES, 256, 256, ACT_RELU);
    gemm_mfma_kernel<<<dim3(MB, 2), 256, 0, stream>>>(
        P0h, P0l, w_h1.h, w_h1.l, nullptr, nullptr, nullptr, nullptr,
        hh1_b, bufF, P1h, P1l, N_NODES, 256, 256, ACT_LEAKY);

    // conv2 + hh2
    sage_mean_kernel<<<NB4, 256, 0, stream>>>(bufF, off, csr_src, P2h, P2l);
    gemm_mfma_kernel<<<dim3(MB, 2), 256, 0, stream>>>(
        P2h, P2l, w_c2l.h, w_c2l.l, P1h, P1l, w_c2r.h, w_c2r.l,
        conv2_lb, nullptr, P0h, P0l, N_NODES, 256, 256, ACT_RELU);
    gemm_mfma_kernel<<<dim3(MB, 2), 256, 0, stream>>>(
        P0h, P0l, w_h2.h, w_h2.l, nullptr, nullptr, nullptr, nullptr,
        hh2_b, bufF, P1h, P1l, N_NODES, 256, 256, ACT_LEAKY);

    // conv3 (O=128) + oo
    sage_mean_kernel<<<NB4, 256, 0, stream>>>(bufF, off, csr_src, P2h, P2l);
    gemm_mfma_kernel<<<dim3(MB, 1), 256, 0, stream>>>(
        P2h, P2l, w_c3l.h, w_c3l.l, P1h, P1l, w_c3r.h, w_c3r.l,
        conv3_lb, nullptr, P0h, P0l, N_NODES, 256, 128, ACT_RELU);
    gemm_mfma_kernel<<<dim3(MB, 1), 256, 0, stream>>>(
        P0h, P0l, w_oo.h, w_oo.l, nullptr, nullptr, nullptr, nullptr,
        oo_b, bufF, nullptr, nullptr, N_NODES, 128, 128, ACT_LEAKY);

    // per-node dots -> per-edge affinity -> 48-group mean
    node_dots_kernel<<<NB4, 256, 0, stream>>>(bufF, lin96_w, lin32_w, nodeDot);
    edge_aff_kernel<<<EB, 256, 0, stream>>>(nodeDot, src, dst, edge_attr,
                                            lin96_b, lin32_b, evals, N_EDGES);
    const int G = N_EDGES / 48;
    group_mean_kernel<<<(G + 255) / 256, 256, 0, stream>>>(evals, (float*)d_out, G);
}

// Round 6
// 483.103 us; speedup vs baseline: 3.4741x; 1.2381x over previous
//
#include <hip/hip_runtime.h>
#include <hip/hip_bf16.h>

#define N_NODES 25000
#define N_EDGES 600000
#define ACT_NONE 0
#define ACT_RELU 1
#define ACT_LEAKY 2

typedef __bf16 bf16x8 __attribute__((ext_vector_type(8)));
typedef float f32x4 __attribute__((ext_vector_type(4)));
typedef unsigned short u16x8 __attribute__((ext_vector_type(8)));
typedef unsigned short u16x4 __attribute__((ext_vector_type(4)));
typedef short s16x4 __attribute__((ext_vector_type(4)));

__device__ __forceinline__ unsigned short f2bf(float x) {
    union { float f; unsigned int u; } v; v.f = x;
    unsigned int r = (v.u + 0x7fffu + ((v.u >> 16) & 1u)) >> 16;
    return (unsigned short)r;
}
__device__ __forceinline__ float bf2f(unsigned short b) {
    union { float f; unsigned int u; } v; v.u = ((unsigned int)b) << 16;
    return v.f;
}

// ---------------------------------------------------------------------------
// CSR construction
// ---------------------------------------------------------------------------
__global__ __launch_bounds__(256) void hist_kernel(const int* __restrict__ dst,
                                                   int* __restrict__ deg, int E) {
    int e = blockIdx.x * 256 + threadIdx.x;
    if (e < E) atomicAdd(&deg[dst[e]], 1);
}

// wave-shuffle scan: 3 barriers per 1024-chunk
__global__ __launch_bounds__(1024) void scan_kernel(const int* __restrict__ deg,
                                                    int* __restrict__ off,
                                                    int* __restrict__ cursor, int n) {
    __shared__ int wsum[16];
    int t = threadIdx.x, w = t >> 6, l = t & 63;
    int carry = 0;
    for (int base = 0; base < n; base += 1024) {
        int v = (base + t < n) ? deg[base + t] : 0;
        int x = v;
        #pragma unroll
        for (int d = 1; d < 64; d <<= 1) {
            int y = __shfl_up(x, d);
            if (l >= d) x += y;
        }
        if (l == 63) wsum[w] = x;
        __syncthreads();
        if (w == 0 && l < 16) {
            int s = wsum[l];
            #pragma unroll
            for (int d = 1; d < 16; d <<= 1) {
                int y = __shfl_up(s, d);
                if (l >= d) s += y;
            }
            wsum[l] = s;
        }
        __syncthreads();
        int woff = (w > 0) ? wsum[w - 1] : 0;
        int excl = x + woff - v;
        if (base + t < n) {
            off[base + t] = carry + excl;
            cursor[base + t] = carry + excl;
        }
        int total = wsum[15];
        __syncthreads();
        carry += total;
    }
    if (t == 0) off[n] = carry;
}

__global__ __launch_bounds__(256) void scatter_kernel(const int* __restrict__ src,
                                                      const int* __restrict__ dst,
                                                      int* __restrict__ cursor,
                                                      int* __restrict__ csr_src, int E) {
    int e = blockIdx.x * 256 + threadIdx.x;
    if (e < E) {
        int d = dst[e];
        int pos = atomicAdd(&cursor[d], 1);
        csr_src[pos] = src[e];
    }
}

// ---------------------------------------------------------------------------
// fp32 -> bf16 hi/lo pair conversion (single large array)
// ---------------------------------------------------------------------------
__global__ __launch_bounds__(256) void convert_kernel(const float* __restrict__ src,
                                                      unsigned short* __restrict__ hi,
                                                      unsigned short* __restrict__ lo, int n) {
    int i = blockIdx.x * 256 + threadIdx.x;
    if (i < n) {
        float x = src[i];
        unsigned short h = f2bf(x);
        hi[i] = h;
        lo[i] = f2bf(x - bf2f(h));
    }
}

// batched conversion for the 10 weight matrices: blockIdx.y = segment
struct CvtBatch {
    const float* src[10];
    unsigned short* hi[10];
    unsigned short* lo[10];
    int count[10];
};
__global__ __launch_bounds__(256) void convert_batch_kernel(CvtBatch b) {
    int seg = blockIdx.y;
    int n = b.count[seg];
    int i = blockIdx.x * 256 + threadIdx.x;
    if (i >= n) return;
    float x = b.src[seg][i];
    unsigned short h = f2bf(x);
    b.hi[seg][i] = h;
    b.lo[seg][i] = f2bf(x - bf2f(h));
}

// ---------------------------------------------------------------------------
// Row quantize: wave per node; per-row absmax -> int16 codes + fp32 scale
// ---------------------------------------------------------------------------
__global__ __launch_bounds__(256) void quant_kernel(const float* __restrict__ h,
                                                    short* __restrict__ qt,
                                                    float* __restrict__ qscale) {
    int node = blockIdx.x * 4 + (threadIdx.x >> 6);
    if (node >= N_NODES) return;
    int lane = threadIdx.x & 63;
    long base = (long)node * 256 + (long)lane * 4;
    f32x4 v = *(const f32x4*)&h[base];
    float m = fmaxf(fmaxf(fabsf(v[0]), fabsf(v[1])), fmaxf(fabsf(v[2]), fabsf(v[3])));
    #pragma unroll
    for (int d = 32; d > 0; d >>= 1) m = fmaxf(m, __shfl_xor(m, d));
    float inv = (m > 0.0f) ? 32767.0f / m : 0.0f;
    float scale = (m > 0.0f) ? m / 32767.0f : 0.0f;
    s16x4 q;
    #pragma unroll
    for (int j = 0; j < 4; ++j) q[j] = (short)(int)rintf(v[j] * inv);
    *(s16x4*)&qt[base] = q;
    if (lane == 0) qscale[node] = scale;
}

// ---------------------------------------------------------------------------
// SAGE mean aggregation over int16-quantized rows: wave per node, 4-deep ILP
// ---------------------------------------------------------------------------
__global__ __launch_bounds__(256) void sage_mean_kernel(const short* __restrict__ qt,
                                                        const float* __restrict__ qscale,
                                                        const int* __restrict__ off,
                                                        const int* __restrict__ csr_src,
                                                        unsigned short* __restrict__ mh,
                                                        unsigned short* __restrict__ ml) {
    int node = blockIdx.x * 4 + (threadIdx.x >> 6);
    if (node >= N_NODES) return;
    int lane = threadIdx.x & 63;
    int s0 = off[node], s1 = off[node + 1];
    f32x4 acc0 = {0.f, 0.f, 0.f, 0.f}, acc1 = {0.f, 0.f, 0.f, 0.f};
    f32x4 acc2 = {0.f, 0.f, 0.f, 0.f}, acc3 = {0.f, 0.f, 0.f, 0.f};
    long loff = (long)lane * 4;
    int e = s0;
    for (; e + 4 <= s1; e += 4) {
        int iA = csr_src[e], iB = csr_src[e + 1], iC = csr_src[e + 2], iD = csr_src[e + 3];
        s16x4 qa = *(const s16x4*)&qt[(long)iA * 256 + loff];
        s16x4 qb = *(const s16x4*)&qt[(long)iB * 256 + loff];
        s16x4 qc = *(const s16x4*)&qt[(long)iC * 256 + loff];
        s16x4 qd = *(const s16x4*)&qt[(long)iD * 256 + loff];
        float sa = qscale[iA], sb = qscale[iB], sc = qscale[iC], sd = qscale[iD];
        #pragma unroll
        for (int j = 0; j < 4; ++j) {
            acc0[j] += sa * (float)qa[j];
            acc1[j] += sb * (float)qb[j];
            acc2[j] += sc * (float)qc[j];
            acc3[j] += sd * (float)qd[j];
        }
    }
    for (; e < s1; ++e) {
        int iA = csr_src[e];
        s16x4 qa = *(const s16x4*)&qt[(long)iA * 256 + loff];
        float sa = qscale[iA];
        #pragma unroll
        for (int j = 0; j < 4; ++j) acc0[j] += sa * (float)qa[j];
    }
    float inv = 1.0f / fmaxf((float)(s1 - s0), 1.0f);
    f32x4 m = ((acc0 + acc1) + (acc2 + acc3)) * inv;
    u16x4 hb, lb;
    #pragma unroll
    for (int j = 0; j < 4; ++j) {
        unsigned short hv = f2bf(m[j]);
        hb[j] = hv;
        lb[j] = f2bf(m[j] - bf2f(hv));
    }
    long base = (long)node * 256 + loff;
    *(u16x4*)&mh[base] = hb;
    *(u16x4*)&ml[base] = lb;
}

// ---------------------------------------------------------------------------
// MFMA split-bf16 dual GEMM with global_load_lds staging + chunk-rotation
// swizzle. LDS tiles [128][32] shorts (64B rows, unpadded).
// Swizzle: lds(r, chunk q) holds global (r, chunk (q + (r>>1))&3); 16B chunks.
// Fragment read of global (row, qk*8) -> lds chunk (qk - (row>>1))&3.
// Bank check: rows 0..7 at fixed qk land on 8 disjoint 16B slots covering all
// 32 banks -> 2 lanes/bank = free.
// ---------------------------------------------------------------------------
__global__ __launch_bounds__(256, 2) void gemm_mfma_kernel(
    const unsigned short* __restrict__ A1h, const unsigned short* __restrict__ A1l,
    const unsigned short* __restrict__ W1h, const unsigned short* __restrict__ W1l,
    const unsigned short* __restrict__ A2h, const unsigned short* __restrict__ A2l,
    const unsigned short* __restrict__ W2h, const unsigned short* __restrict__ W2l,
    const float* __restrict__ bias,
    float* __restrict__ Cf, unsigned short* __restrict__ Ch, unsigned short* __restrict__ Cl,
    int M, int K, int O, int act)
{
    __shared__ unsigned short sAh[128][32];
    __shared__ unsigned short sAl[128][32];
    __shared__ unsigned short sWh[128][32];
    __shared__ unsigned short sWl[128][32];

    int tid = threadIdx.x;
    int row0 = blockIdx.x * 128;
    int col0 = blockIdx.y * 128;
    int wid = tid >> 6, lane = tid & 63;
    int wm = (wid >> 1) * 64, wo = (wid & 1) * 64;
    int fr = lane & 15, qk = lane >> 4;

    int rr = lane >> 2, qq = lane & 3;   // staging: lane covers lds row r0+rr, chunk qq

    f32x4 acc[4][4] = {};

    for (int pass = 0; pass < 2; ++pass) {
        const unsigned short* Ah = pass ? A2h : A1h;
        const unsigned short* Al = pass ? A2l : A1l;
        const unsigned short* Wh = pass ? W2h : W1h;
        const unsigned short* Wl = pass ? W2l : W1l;
        if (Ah == nullptr) continue;
        for (int k0 = 0; k0 < K; k0 += 32) {
            // ---- stage 4 tiles via global_load_lds (wave-uniform LDS base) ----
            #pragma unroll
            for (int i = 0; i < 2; ++i) {
                int rb = wid * 32 + i * 16;          // uniform per wave
                int r = rb + rr;                     // this lane's lds row
                int gc = ((qq + (r >> 1)) & 3) * 8;  // global chunk col (shorts)
                long ar = (long)(row0 + r);
                if (ar > M - 1) ar = M - 1;          // clamp; masked at C-write
                long wr = (long)(col0 + r);
                const unsigned short* pAh = Ah + ar * K + k0 + gc;
                const unsigned short* pAl = Al + ar * K + k0 + gc;
                const unsigned short* pWh = Wh + wr * K + k0 + gc;
                const unsigned short* pWl = Wl + wr * K + k0 + gc;
                __builtin_amdgcn_global_load_lds(
                    (const __attribute__((address_space(1))) unsigned int*)pAh,
                    (__attribute__((address_space(3))) unsigned int*)&sAh[rb][0], 16, 0, 0);
                __builtin_amdgcn_global_load_lds(
                    (const __attribute__((address_space(1))) unsigned int*)pAl,
                    (__attribute__((address_space(3))) unsigned int*)&sAl[rb][0], 16, 0, 0);
                __builtin_amdgcn_global_load_lds(
                    (const __attribute__((address_space(1))) unsigned int*)pWh,
                    (__attribute__((address_space(3))) unsigned int*)&sWh[rb][0], 16, 0, 0);
                __builtin_amdgcn_global_load_lds(
                    (const __attribute__((address_space(1))) unsigned int*)pWl,
                    (__attribute__((address_space(3))) unsigned int*)&sWl[rb][0], 16, 0, 0);
            }
            __syncthreads();   // drains vmcnt + lgkmcnt

            bf16x8 ah[4], al[4], bh[4], bl[4];
            #pragma unroll
            for (int i = 0; i < 4; ++i) {
                int rowA = wm + i * 16 + fr;
                int offA = rowA * 32 + 8 * ((qk - (rowA >> 1)) & 3);
                ah[i] = *(const bf16x8*)(&sAh[0][0] + offA);
                al[i] = *(const bf16x8*)(&sAl[0][0] + offA);
                int rowB = wo + i * 16 + fr;
                int offB = rowB * 32 + 8 * ((qk - (rowB >> 1)) & 3);
                bh[i] = *(const bf16x8*)(&sWh[0][0] + offB);
                bl[i] = *(const bf16x8*)(&sWl[0][0] + offB);
            }
            #pragma unroll
            for (int i = 0; i < 4; ++i) {
                #pragma unroll
                for (int j = 0; j < 4; ++j) {
                    acc[i][j] = __builtin_amdgcn_mfma_f32_16x16x32_bf16(ah[i], bh[j], acc[i][j], 0, 0, 0);
                    acc[i][j] = __builtin_amdgcn_mfma_f32_16x16x32_bf16(ah[i], bl[j], acc[i][j], 0, 0, 0);
                    acc[i][j] = __builtin_amdgcn_mfma_f32_16x16x32_bf16(al[i], bh[j], acc[i][j], 0, 0, 0);
                }
            }
            __syncthreads();
        }
    }

    // epilogue: C/D layout col=lane&15, row=(lane>>4)*4+reg  [m89-verified]
    int rgrp = (lane >> 4) * 4;
    int cl_ = lane & 15;
    #pragma unroll
    for (int i = 0; i < 4; ++i) {
        #pragma unroll
        for (int j = 0; j < 4; ++j) {
            int gcol = col0 + wo + j * 16 + cl_;
            float bv = bias[gcol];
            #pragma unroll
            for (int r = 0; r < 4; ++r) {
                int grow = row0 + wm + i * 16 + rgrp + r;
                if (grow < M) {
                    float v = acc[i][j][r] + bv;
                    if (act == ACT_RELU)       v = fmaxf(v, 0.0f);
                    else if (act == ACT_LEAKY) v = (v > 0.0f) ? v : 0.01f * v;
                    long idx = (long)grow * O + gcol;
                    if (Cf) Cf[idx] = v;
                    if (Ch) {
                        unsigned short hbits = f2bf(v);
                        Ch[idx] = hbits;
                        Cl[idx] = f2bf(v - bf2f(hbits));
                    }
                }
            }
        }
    }
}

// ---------------------------------------------------------------------------
// Per-node edge-MLP dot products: nodeDot[n] = {dL96, dR96, dL32, dR32}
// ---------------------------------------------------------------------------
__global__ __launch_bounds__(256) void node_dots_kernel(const float* __restrict__ h,
                                                        const float* __restrict__ w96,
                                                        const float* __restrict__ w32,
                                                        float* __restrict__ nodeDot) {
    int node = blockIdx.x * 4 + (threadIdx.x >> 6);
    if (node >= N_NODES) return;
    int lane = threadIdx.x & 63;
    const float* row = h + (long)node * 128;
    float h0 = row[lane];
    float h1 = row[64 + lane];
    float pL96 = h0 * w96[lane];
    float pR96 = h0 * w96[96 + lane];
    float pL32 = 0.0f, pR32 = 0.0f;
    if (lane < 32) {
        pL96 += h1 * w96[64 + lane];
        pR96 += h1 * w96[160 + lane];
    } else {
        int k = lane - 32;
        pL32 = h1 * w32[k];
        pR32 = h1 * w32[32 + k];
    }
    #pragma unroll
    for (int m = 32; m > 0; m >>= 1) {
        pL96 += __shfl_xor(pL96, m);
        pR96 += __shfl_xor(pR96, m);
        pL32 += __shfl_xor(pL32, m);
        pR32 += __shfl_xor(pR32, m);
    }
    if (lane == 0) {
        f32x4 v = {pL96, pR96, pL32, pR32};
        *(f32x4*)&nodeDot[(long)node * 4] = v;
    }
}

// ---------------------------------------------------------------------------
// Per-edge affinity from node dots
// ---------------------------------------------------------------------------
__global__ __launch_bounds__(256) void edge_aff_kernel(const float* __restrict__ nodeDot,
                                                       const int* __restrict__ src,
                                                       const int* __restrict__ dst,
                                                       const float* __restrict__ eattr,
                                                       const float* __restrict__ b96,
                                                       const float* __restrict__ b32,
                                                       float* __restrict__ vals, int E) {
    int e = blockIdx.x * 256 + threadIdx.x;
    if (e >= E) return;
    f32x4 a = *(const f32x4*)&nodeDot[(long)src[e] * 4];
    f32x4 b = *(const f32x4*)&nodeDot[(long)dst[e] * 4];
    float f96  = fmaxf(a[0] + b[1] + b96[0], 0.0f);
    float f32v = fmaxf(a[2] + b[3] + b32[0], 0.0f);
    vals[e] = f96 * eattr[e] + f32v;
}

__global__ __launch_bounds__(256) void group_mean_kernel(const float* __restrict__ vals,
                                                         float* __restrict__ out, int G) {
    int g = blockIdx.x * 256 + threadIdx.x;
    if (g >= G) return;
    float s = 0.0f;
    #pragma unroll
    for (int k = 0; k < 48; ++k) s += vals[g * 48 + k];
    out[g] = s * (1.0f / 48.0f);
}

// ---------------------------------------------------------------------------
extern "C" void kernel_launch(void* const* d_in, const int* in_sizes, int n_in,
                              void* d_out, int out_size, void* d_ws, size_t ws_size,
                              hipStream_t stream) {
    const float* x         = (const float*)d_in[0];
    const int*   edge_idx  = (const int*)d_in[1];
    const float* edge_attr = (const float*)d_in[2];
    const float* prelin_w  = (const float*)d_in[4];
    const float* prelin_b  = (const float*)d_in[5];
    const float* conv1_lw  = (const float*)d_in[6];
    const float* conv1_lb  = (const float*)d_in[7];
    const float* conv1_rw  = (const float*)d_in[8];
    const float* conv2_lw  = (const float*)d_in[9];
    const float* conv2_lb  = (const float*)d_in[10];
    const float* conv2_rw  = (const float*)d_in[11];
    const float* conv3_lw  = (const float*)d_in[12];
    const float* conv3_lb  = (const float*)d_in[13];
    const float* conv3_rw  = (const float*)d_in[14];
    const float* hh1_w     = (const float*)d_in[15];
    const float* hh1_b     = (const float*)d_in[16];
    const float* hh2_w     = (const float*)d_in[17];
    const float* hh2_b     = (const float*)d_in[18];
    const float* oo_w      = (const float*)d_in[19];
    const float* oo_b      = (const float*)d_in[20];
    const float* lin96_w   = (const float*)d_in[21];
    const float* lin96_b   = (const float*)d_in[22];
    const float* lin32_w   = (const float*)d_in[23];
    const float* lin32_b   = (const float*)d_in[24];

    const int* src = edge_idx;
    const int* dst = edge_idx + N_EDGES;

    // ---- workspace carve-up ----
    char* wsp = (char*)d_ws;
    size_t used = 0;
    auto alloc = [&](size_t bytes) -> char* {
        char* r = wsp;
        size_t pad = (bytes + 255) & ~(size_t)255;
        wsp += pad; used += pad;
        return r;
    };
    float* bufF = (float*)alloc((size_t)N_NODES * 256 * 4);
    unsigned short* P0h = (unsigned short*)alloc((size_t)N_NODES * 256 * 2);
    unsigned short* P0l = (unsigned short*)alloc((size_t)N_NODES * 256 * 2);
    unsigned short* P1h = (unsigned short*)alloc((size_t)N_NODES * 256 * 2);
    unsigned short* P1l = (unsigned short*)alloc((size_t)N_NODES * 256 * 2);
    unsigned short* P2h = (unsigned short*)alloc((size_t)N_NODES * 256 * 2);
    unsigned short* P2l = (unsigned short*)alloc((size_t)N_NODES * 256 * 2);
    short* qtab    = (short*)alloc((size_t)N_NODES * 256 * 2);
    float* qscale  = (float*)alloc((size_t)N_NODES * 4);
    float* evals   = (float*)alloc((size_t)N_EDGES * 4);
    float* nodeDot = (float*)alloc((size_t)N_NODES * 4 * 4);
    int* deg       = (int*)alloc((size_t)N_NODES * 4);
    int* off       = (int*)alloc((size_t)(N_NODES + 1) * 4);
    int* cursor    = (int*)alloc((size_t)N_NODES * 4);
    int* csr_src   = (int*)alloc((size_t)N_EDGES * 4);

    struct WP { unsigned short *h, *l; };
    auto wpair = [&](int n) -> WP {
        WP w; w.h = (unsigned short*)alloc((size_t)n * 2);
        w.l = (unsigned short*)alloc((size_t)n * 2); return w;
    };
    WP w_pre = wpair(256 * 128);
    WP w_c1l = wpair(256 * 256), w_c1r = wpair(256 * 256);
    WP w_c2l = wpair(256 * 256), w_c2r = wpair(256 * 256);
    WP w_c3l = wpair(128 * 256), w_c3r = wpair(128 * 256);
    WP w_h1  = wpair(256 * 256), w_h2 = wpair(256 * 256);
    WP w_oo  = wpair(128 * 128);

    if (used > ws_size) return;  // loud failure rather than silent corruption

    const int EB = (N_EDGES + 255) / 256;
    const int MB = (N_NODES + 127) / 128;  // 196
    const int NB4 = (N_NODES + 3) / 4;     // 6250 (wave-per-node kernels)

    // CSR build
    (void)hipMemsetAsync(deg, 0, N_NODES * sizeof(int), stream);
    hist_kernel<<<EB, 256, 0, stream>>>(dst, deg, N_EDGES);
    scan_kernel<<<1, 1024, 0, stream>>>(deg, off, cursor, N_NODES);
    scatter_kernel<<<EB, 256, 0, stream>>>(src, dst, cursor, csr_src, N_EDGES);

    // conversions: x separately, 10 weights in ONE batched launch
    convert_kernel<<<((N_NODES * 128) + 255) / 256, 256, 0, stream>>>(x, P0h, P0l, N_NODES * 128);
    CvtBatch cb;
    const float* wsrc[10] = {prelin_w, conv1_lw, conv1_rw, conv2_lw, conv2_rw,
                             conv3_lw, conv3_rw, hh1_w, hh2_w, oo_w};
    WP wdst[10] = {w_pre, w_c1l, w_c1r, w_c2l, w_c2r, w_c3l, w_c3r, w_h1, w_h2, w_oo};
    int wcnt[10] = {256 * 128, 256 * 256, 256 * 256, 256 * 256, 256 * 256,
                    128 * 256, 128 * 256, 256 * 256, 256 * 256, 128 * 128};
    for (int i = 0; i < 10; ++i) {
        cb.src[i] = wsrc[i]; cb.hi[i] = wdst[i].h; cb.lo[i] = wdst[i].l; cb.count[i] = wcnt[i];
    }
    convert_batch_kernel<<<dim3((65536 + 255) / 256, 10), 256, 0, stream>>>(cb);

    // prelin: h1 = relu(x W^T + b) -> bufF(f32) + P1(pair)
    gemm_mfma_kernel<<<dim3(MB, 2), 256, 0, stream>>>(
        P0h, P0l, w_pre.h, w_pre.l, nullptr, nullptr, nullptr, nullptr,
        prelin_b, bufF, P1h, P1l, N_NODES, 128, 256, ACT_RELU);

    // conv1 + hh1
    quant_kernel<<<NB4, 256, 0, stream>>>(bufF, qtab, qscale);
    sage_mean_kernel<<<NB4, 256, 0, stream>>>(qtab, qscale, off, csr_src, P2h, P2l);
    gemm_mfma_kernel<<<dim3(MB, 2), 256, 0, stream>>>(
        P2h, P2l, w_c1l.h, w_c1l.l, P1h, P1l, w_c1r.h, w_c1r.l,
        conv1_lb, nullptr, P0h, P0l, N_NODES, 256, 256, ACT_RELU);
    gemm_mfma_kernel<<<dim3(MB, 2), 256, 0, stream>>>(
        P0h, P0l, w_h1.h, w_h1.l, nullptr, nullptr, nullptr, nullptr,
        hh1_b, bufF, P1h, P1l, N_NODES, 256, 256, ACT_LEAKY);

    // conv2 + hh2
    quant_kernel<<<NB4, 256, 0, stream>>>(bufF, qtab, qscale);
    sage_mean_kernel<<<NB4, 256, 0, stream>>>(qtab, qscale, off, csr_src, P2h, P2l);
    gemm_mfma_kernel<<<dim3(MB, 2), 256, 0, stream>>>(
        P2h, P2l, w_c2l.h, w_c2l.l, P1h, P1l, w_c2r.h, w_c2r.l,
        conv2_lb, nullptr, P0h, P0l, N_NODES, 256, 256, ACT_RELU);
    gemm_mfma_kernel<<<dim3(MB, 2), 256, 0, stream>>>(
        P0h, P0l, w_h2.h, w_h2.l, nullptr, nullptr, nullptr, nullptr,
        hh2_b, bufF, P1h, P1l, N_NODES, 256, 256, ACT_LEAKY);

    // conv3 (O=128) + oo
    quant_kernel<<<NB4, 256, 0, stream>>>(bufF, qtab, qscale);
    sage_mean_kernel<<<NB4, 256, 0, stream>>>(qtab, qscale, off, csr_src, P2h, P2l);
    gemm_mfma_kernel<<<dim3(MB, 1), 256, 0, stream>>>(
        P2h, P2l, w_c3l.h, w_c3l.l, P1h, P1l, w_c3r.h, w_c3r.l,
        conv3_lb, nullptr, P0h, P0l, N_NODES, 256, 128, ACT_RELU);
    gemm_mfma_kernel<<<dim3(MB, 1), 256, 0, stream>>>(
        P0h, P0l, w_oo.h, w_oo.l, nullptr, nullptr, nullptr, nullptr,
        oo_b, bufF, nullptr, nullptr, N_NODES, 128, 128, ACT_LEAKY);

    // per-node dots -> per-edge affinity -> 48-group mean
    node_dots_kernel<<<NB4, 256, 0, stream>>>(bufF, lin96_w, lin32_w, nodeDot);
    edge_aff_kernel<<<EB, 256, 0, stream>>>(nodeDot, src, dst, edge_attr,
                                            lin96_b, lin32_b, evals, N_EDGES);
    const int G = N_EDGES / 48;
    group_mean_kernel<<<(G + 255) / 256, 256, 0, stream>>>(evals, (float*)d_out, G);
}